// Round 1
// baseline (4358.942 us; speedup 1.0000x reference)
//
#include <hip/hip_runtime.h>

// GAT layer: N=100000 nodes, E=1600000 edges, F=128, H=3 heads, D=16.
// out = (1-lin)*segment_softmax_msg + lin*feat
constexpr int F = 128;
constexpr int H = 3;
constexpr int D = 16;
constexpr int C = H * D;  // 48
#define NEG_SLOPE 0.2f

// ---------------- K1: feat = x @ W^T ; el/er = <feat, attn_l/r> per head ----
// 64 nodes per block, 256 threads: 4 threads/node x 12 channels each.
__global__ __launch_bounds__(256) void feat_el_er_kernel(
    const float* __restrict__ x, const float* __restrict__ W,
    const float* __restrict__ attn_l, const float* __restrict__ attn_r,
    float* __restrict__ feat, float* __restrict__ el, float* __restrict__ er,
    int N)
{
    __shared__ float xs[64][F + 4];
    __shared__ float Ws[C][F + 4];
    const int tid = threadIdx.x;
    const int base = blockIdx.x * 64;

    // stage W (48x128 = 1536 float4)
    for (int i = tid; i < C * F / 4; i += 256) {
        int c = i >> 5, k4 = i & 31;
        float4 v = *reinterpret_cast<const float4*>(&W[c * F + k4 * 4]);
        *reinterpret_cast<float4*>(&Ws[c][k4 * 4]) = v;
    }
    // stage x tile (64x128 = 2048 float4)
    for (int i = tid; i < 64 * F / 4; i += 256) {
        int nl = i >> 5, k4 = i & 31;
        int n = base + nl;
        if (n < N) {
            float4 v = *reinterpret_cast<const float4*>(&x[(size_t)n * F + k4 * 4]);
            *reinterpret_cast<float4*>(&xs[nl][k4 * 4]) = v;
        }
    }
    __syncthreads();

    const int nl = tid >> 2;        // node within tile
    const int cg = tid & 3;         // channel group
    const int n = base + nl;
    const int c0 = cg * 12;

    if (n < N) {
        float acc[12];
#pragma unroll
        for (int j = 0; j < 12; ++j) acc[j] = 0.f;

        for (int k4 = 0; k4 < F / 4; ++k4) {
            float4 xv = *reinterpret_cast<const float4*>(&xs[nl][k4 * 4]);
#pragma unroll
            for (int j = 0; j < 12; ++j) {
                float4 wv = *reinterpret_cast<const float4*>(&Ws[c0 + j][k4 * 4]);
                acc[j] += xv.x * wv.x + xv.y * wv.y + xv.z * wv.z + xv.w * wv.w;
            }
        }
        // write feat (3 x float4, 16B-aligned since c0 % 4 == 0)
#pragma unroll
        for (int j = 0; j < 12; j += 4) {
            float4 v = make_float4(acc[j], acc[j + 1], acc[j + 2], acc[j + 3]);
            *reinterpret_cast<float4*>(&feat[(size_t)n * C + c0 + j]) = v;
        }
        // partial el/er per head over this thread's 12 channels
        float pl[H] = {0.f, 0.f, 0.f}, pr[H] = {0.f, 0.f, 0.f};
#pragma unroll
        for (int j = 0; j < 12; ++j) {
            int c = c0 + j;
            int h = c >> 4;
            pl[h] += acc[j] * attn_l[c];
            pr[h] += acc[j] * attn_r[c];
        }
        // reduce across the 4 lanes of this node (lanes differ in low 2 bits)
#pragma unroll
        for (int h = 0; h < H; ++h) {
            pl[h] += __shfl_xor(pl[h], 1);
            pl[h] += __shfl_xor(pl[h], 2);
            pr[h] += __shfl_xor(pr[h], 1);
            pr[h] += __shfl_xor(pr[h], 2);
        }
        if (cg == 0) {
#pragma unroll
            for (int h = 0; h < H; ++h) {
                el[(size_t)n * H + h] = pl[h];
                er[(size_t)n * H + h] = pr[h];
            }
        }
    }
}

// ---------------- K2: edge scatter (softmax numerator/denominator) ---------
// exp WITHOUT max subtraction: scores are bounded (|e| < ~8), exp() safe in
// f32; softmax is shift-invariant so result matches the reference.
__global__ __launch_bounds__(256) void edge_kernel(
    const int* __restrict__ src, const int* __restrict__ dst,
    const float* __restrict__ el, const float* __restrict__ er,
    const float* __restrict__ feat,
    float* __restrict__ num, float* __restrict__ denom, int E)
{
    int e = blockIdx.x * blockDim.x + threadIdx.x;
    if (e >= E) return;
    int s = src[e], d = dst[e];

    float w[H];
#pragma unroll
    for (int h = 0; h < H; ++h) {
        float t = el[(size_t)s * H + h] + er[(size_t)d * H + h];
        t = t > 0.f ? t : NEG_SLOPE * t;
        w[h] = expf(t);
        atomicAdd(&denom[(size_t)d * H + h], w[h]);
    }
    const float* fs = &feat[(size_t)s * C];
    float* nd = &num[(size_t)d * C];
#pragma unroll
    for (int h = 0; h < H; ++h) {
#pragma unroll
        for (int k = 0; k < D; k += 4) {
            float4 f = *reinterpret_cast<const float4*>(&fs[h * D + k]);
            atomicAdd(&nd[h * D + k + 0], w[h] * f.x);
            atomicAdd(&nd[h * D + k + 1], w[h] * f.y);
            atomicAdd(&nd[h * D + k + 2], w[h] * f.z);
            atomicAdd(&nd[h * D + k + 3], w[h] * f.w);
        }
    }
}

// ---------------- K3: out = (1-lin)*num/denom + lin*feat -------------------
__global__ __launch_bounds__(256) void out_kernel(
    const float* __restrict__ feat, const float* __restrict__ num,
    const float* __restrict__ denom, const float* __restrict__ lin,
    float* __restrict__ out, int N)
{
    int i = blockIdx.x * blockDim.x + threadIdx.x;  // float4 index
    int total = N * C / 4;
    if (i >= total) return;
    int n = i / 12;
    int q = i - n * 12;
    int c = q * 4;
    int h = c >> 4;

    float den = denom[(size_t)n * H + h];
    float inv = den > 0.f ? 1.f / den : 0.f;  // zero-degree nodes -> msg = 0
    float4 m = *reinterpret_cast<const float4*>(&num[(size_t)n * C + c]);
    float4 f = *reinterpret_cast<const float4*>(&feat[(size_t)n * C + c]);
    float l = lin[n];
    float om = 1.f - l;
    float4 o;
    o.x = om * (m.x * inv) + l * f.x;
    o.y = om * (m.y * inv) + l * f.y;
    o.z = om * (m.z * inv) + l * f.z;
    o.w = om * (m.w * inv) + l * f.w;
    *reinterpret_cast<float4*>(&out[(size_t)i * 4]) = o;
}

extern "C" void kernel_launch(void* const* d_in, const int* in_sizes, int n_in,
                              void* d_out, int out_size, void* d_ws, size_t ws_size,
                              hipStream_t stream)
{
    const float* x      = (const float*)d_in[0];
    const float* W      = (const float*)d_in[1];
    const float* attn_l = (const float*)d_in[2];
    const float* attn_r = (const float*)d_in[3];
    const float* lin    = (const float*)d_in[4];
    const int*   src    = (const int*)d_in[5];
    const int*   dst    = (const int*)d_in[6];
    const int N = in_sizes[4];
    const int E = in_sizes[5];
    float* out = (float*)d_out;

    // workspace layout
    float* feat  = (float*)d_ws;                 // N*C
    float* el    = feat + (size_t)N * C;         // N*H
    float* er    = el   + (size_t)N * H;         // N*H
    float* num   = er   + (size_t)N * H;         // N*C   (zeroed)
    float* denom = num  + (size_t)N * C;         // N*H   (zeroed, contiguous w/ num)

    hipMemsetAsync(num, 0, (size_t)N * (C + H) * sizeof(float), stream);

    feat_el_er_kernel<<<(N + 63) / 64, 256, 0, stream>>>(
        x, W, attn_l, attn_r, feat, el, er, N);
    edge_kernel<<<(E + 255) / 256, 256, 0, stream>>>(
        src, dst, el, er, feat, num, denom, E);
    out_kernel<<<(N * C / 4 + 255) / 256, 256, 0, stream>>>(
        feat, num, denom, lin, out, N);
}

// Round 2
// 619.865 us; speedup vs baseline: 7.0321x; 7.0321x over previous
//
#include <hip/hip_runtime.h>

// GAT layer: N=100000 nodes, E=1600000 edges, F=128, H=3 heads, D=16.
// Strategy: CSR-ify edges on device (no f32 atomics), node-parallel gather.
constexpr int F = 128;
constexpr int H = 3;
constexpr int D = 16;
constexpr int C = H * D;  // 48
#define NEG_SLOPE 0.2f

// ---------------- K1: feat = x @ W^T ; el/er = <feat, attn_l/r> per head ----
// 64 nodes per block, 256 threads: 4 threads/node x 12 channels each.
__global__ __launch_bounds__(256) void feat_el_er_kernel(
    const float* __restrict__ x, const float* __restrict__ W,
    const float* __restrict__ attn_l, const float* __restrict__ attn_r,
    float* __restrict__ feat, float* __restrict__ el, float* __restrict__ er,
    int N)
{
    __shared__ float xs[64][F + 4];
    __shared__ float Ws[C][F + 4];
    const int tid = threadIdx.x;
    const int base = blockIdx.x * 64;

    for (int i = tid; i < C * F / 4; i += 256) {
        int c = i >> 5, k4 = i & 31;
        float4 v = *reinterpret_cast<const float4*>(&W[c * F + k4 * 4]);
        *reinterpret_cast<float4*>(&Ws[c][k4 * 4]) = v;
    }
    for (int i = tid; i < 64 * F / 4; i += 256) {
        int nl = i >> 5, k4 = i & 31;
        int n = base + nl;
        if (n < N) {
            float4 v = *reinterpret_cast<const float4*>(&x[(size_t)n * F + k4 * 4]);
            *reinterpret_cast<float4*>(&xs[nl][k4 * 4]) = v;
        }
    }
    __syncthreads();

    const int nl = tid >> 2;
    const int cg = tid & 3;
    const int n = base + nl;
    const int c0 = cg * 12;

    if (n < N) {
        float acc[12];
#pragma unroll
        for (int j = 0; j < 12; ++j) acc[j] = 0.f;

        for (int k4 = 0; k4 < F / 4; ++k4) {
            float4 xv = *reinterpret_cast<const float4*>(&xs[nl][k4 * 4]);
#pragma unroll
            for (int j = 0; j < 12; ++j) {
                float4 wv = *reinterpret_cast<const float4*>(&Ws[c0 + j][k4 * 4]);
                acc[j] += xv.x * wv.x + xv.y * wv.y + xv.z * wv.z + xv.w * wv.w;
            }
        }
#pragma unroll
        for (int j = 0; j < 12; j += 4) {
            float4 v = make_float4(acc[j], acc[j + 1], acc[j + 2], acc[j + 3]);
            *reinterpret_cast<float4*>(&feat[(size_t)n * C + c0 + j]) = v;
        }
        float pl[H] = {0.f, 0.f, 0.f}, pr[H] = {0.f, 0.f, 0.f};
#pragma unroll
        for (int j = 0; j < 12; ++j) {
            int c = c0 + j;
            int h = c >> 4;
            pl[h] += acc[j] * attn_l[c];
            pr[h] += acc[j] * attn_r[c];
        }
#pragma unroll
        for (int h = 0; h < H; ++h) {
            pl[h] += __shfl_xor(pl[h], 1);
            pl[h] += __shfl_xor(pl[h], 2);
            pr[h] += __shfl_xor(pr[h], 1);
            pr[h] += __shfl_xor(pr[h], 2);
        }
        if (cg == 0) {
#pragma unroll
            for (int h = 0; h < H; ++h) {
                el[(size_t)n * H + h] = pl[h];
                er[(size_t)n * H + h] = pr[h];
            }
        }
    }
}

// ---------------- K2a: degree histogram -----------------------------------
__global__ __launch_bounds__(256) void hist_kernel(
    const int* __restrict__ dst, int* __restrict__ deg, int E)
{
    int e = blockIdx.x * blockDim.x + threadIdx.x;
    if (e < E) atomicAdd(&deg[dst[e]], 1);
}

// ---------------- K2b: single-block exclusive scan of deg -> off, cursor ---
__global__ __launch_bounds__(1024) void scan_kernel(
    const int* __restrict__ deg, int* __restrict__ off,
    int* __restrict__ cursor, int N)
{
    __shared__ int sums[1024];
    const int tid = threadIdx.x;
    const int chunk = (N + 1023) / 1024;
    const int start = tid * chunk;
    const int end = min(start + chunk, N);

    int s = 0;
    for (int i = start; i < end; ++i) s += deg[i];
    sums[tid] = s;
    __syncthreads();
    // Hillis-Steele inclusive scan
    for (int d = 1; d < 1024; d <<= 1) {
        int v = (tid >= d) ? sums[tid - d] : 0;
        __syncthreads();
        sums[tid] += v;
        __syncthreads();
    }
    int run = (tid == 0) ? 0 : sums[tid - 1];
    for (int i = start; i < end; ++i) {
        off[i] = run;
        cursor[i] = run;
        run += deg[i];
    }
    if (tid == 1023) off[N] = sums[1023];
}

// ---------------- K2c: scatter src into CSR order --------------------------
__global__ __launch_bounds__(256) void scatter_kernel(
    const int* __restrict__ src, const int* __restrict__ dst,
    int* __restrict__ cursor, int* __restrict__ srcs, int E)
{
    int e = blockIdx.x * blockDim.x + threadIdx.x;
    if (e >= E) return;
    int d = dst[e];
    int pos = atomicAdd(&cursor[d], 1);
    srcs[pos] = src[e];
}

// ---------------- K3: node-parallel gather + softmax + blend ---------------
// 4 lanes per node; each lane owns 12 channels. num/denom live in registers.
// exp without max-subtraction: |e| < ~10 so exp() is safe in f32, and softmax
// is shift-invariant -> identical result.
__global__ __launch_bounds__(256) void gather_kernel(
    const int* __restrict__ off, const int* __restrict__ srcs,
    const float* __restrict__ el, const float* __restrict__ er,
    const float* __restrict__ feat, const float* __restrict__ lin,
    float* __restrict__ out, int N)
{
    const int tid = threadIdx.x;
    const int nl = tid >> 2;
    const int cg = tid & 3;
    const int n = blockIdx.x * 64 + nl;
    if (n >= N) return;
    const int c0 = cg * 12;

    float ern[H];
#pragma unroll
    for (int h = 0; h < H; ++h) ern[h] = er[(size_t)n * H + h];

    float acc[12];
#pragma unroll
    for (int j = 0; j < 12; ++j) acc[j] = 0.f;
    float den[H] = {0.f, 0.f, 0.f};

    const int start = off[n];
    const int end = off[n + 1];
    for (int e = start; e < end; ++e) {
        int s = srcs[e];
        float w[H];
#pragma unroll
        for (int h = 0; h < H; ++h) {
            float t = el[(size_t)s * H + h] + ern[h];
            t = t > 0.f ? t : NEG_SLOPE * t;
            w[h] = __expf(t);
            den[h] += w[h];
        }
        const float* fs = &feat[(size_t)s * C + c0];
#pragma unroll
        for (int j = 0; j < 12; j += 4) {
            float4 f = *reinterpret_cast<const float4*>(&fs[j]);
            float wh = w[(c0 + j) >> 4];  // c0+j..c0+j+3 share a head
            acc[j + 0] += wh * f.x;
            acc[j + 1] += wh * f.y;
            acc[j + 2] += wh * f.z;
            acc[j + 3] += wh * f.w;
        }
    }

    const float l = lin[n];
    const float om = 1.f - l;
#pragma unroll
    for (int j = 0; j < 12; j += 4) {
        int h = (c0 + j) >> 4;
        float inv = den[h] > 0.f ? 1.f / den[h] : 0.f;  // deg-0 node -> msg 0
        float4 f = *reinterpret_cast<const float4*>(&feat[(size_t)n * C + c0 + j]);
        float4 o;
        o.x = om * (acc[j + 0] * inv) + l * f.x;
        o.y = om * (acc[j + 1] * inv) + l * f.y;
        o.z = om * (acc[j + 2] * inv) + l * f.z;
        o.w = om * (acc[j + 3] * inv) + l * f.w;
        *reinterpret_cast<float4*>(&out[(size_t)n * C + c0 + j]) = o;
    }
}

extern "C" void kernel_launch(void* const* d_in, const int* in_sizes, int n_in,
                              void* d_out, int out_size, void* d_ws, size_t ws_size,
                              hipStream_t stream)
{
    const float* x      = (const float*)d_in[0];
    const float* W      = (const float*)d_in[1];
    const float* attn_l = (const float*)d_in[2];
    const float* attn_r = (const float*)d_in[3];
    const float* lin    = (const float*)d_in[4];
    const int*   src    = (const int*)d_in[5];
    const int*   dst    = (const int*)d_in[6];
    const int N = in_sizes[4];
    const int E = in_sizes[5];
    float* out = (float*)d_out;

    // workspace layout
    float* feat   = (float*)d_ws;                    // N*C
    float* el     = feat + (size_t)N * C;            // N*H
    float* er     = el   + (size_t)N * H;            // N*H
    int*   deg    = (int*)(er + (size_t)N * H);      // N      (zeroed)
    int*   off    = deg + N;                         // N+1
    int*   cursor = off + N + 1;                     // N
    int*   srcs   = cursor + N;                      // E

    hipMemsetAsync(deg, 0, (size_t)N * sizeof(int), stream);

    feat_el_er_kernel<<<(N + 63) / 64, 256, 0, stream>>>(
        x, W, attn_l, attn_r, feat, el, er, N);
    hist_kernel<<<(E + 255) / 256, 256, 0, stream>>>(dst, deg, E);
    scan_kernel<<<1, 1024, 0, stream>>>(deg, off, cursor, N);
    scatter_kernel<<<(E + 255) / 256, 256, 0, stream>>>(src, dst, cursor, srcs, E);
    gather_kernel<<<(N + 63) / 64, 256, 0, stream>>>(
        off, srcs, el, er, feat, lin, out, N);
}

// Round 4
// 414.817 us; speedup vs baseline: 10.5081x; 1.4943x over previous
//
#include <hip/hip_runtime.h>

// GAT layer: N=100000 nodes, E=1600000 edges, F=128, H=3 heads, D=16.
// Strategy: CSR-ify edges on device (no f32 atomics), node-parallel gather.
constexpr int F = 128;
constexpr int H = 3;
constexpr int D = 16;
constexpr int C = H * D;  // 48
#define NEG_SLOPE 0.2f

// ---------------- K1: feat = x @ W^T ; el/er = <feat, attn_l/r> per head ----
__global__ __launch_bounds__(256) void feat_el_er_kernel(
    const float* __restrict__ x, const float* __restrict__ W,
    const float* __restrict__ attn_l, const float* __restrict__ attn_r,
    float* __restrict__ feat, float* __restrict__ el, float* __restrict__ er,
    int N)
{
    __shared__ float xs[64][F + 4];
    __shared__ float Ws[C][F + 4];
    const int tid = threadIdx.x;
    const int base = blockIdx.x * 64;

    for (int i = tid; i < C * F / 4; i += 256) {
        int c = i >> 5, k4 = i & 31;
        float4 v = *reinterpret_cast<const float4*>(&W[c * F + k4 * 4]);
        *reinterpret_cast<float4*>(&Ws[c][k4 * 4]) = v;
    }
    for (int i = tid; i < 64 * F / 4; i += 256) {
        int nl = i >> 5, k4 = i & 31;
        int n = base + nl;
        if (n < N) {
            float4 v = *reinterpret_cast<const float4*>(&x[(size_t)n * F + k4 * 4]);
            *reinterpret_cast<float4*>(&xs[nl][k4 * 4]) = v;
        }
    }
    __syncthreads();

    const int nl = tid >> 2;
    const int cg = tid & 3;
    const int n = base + nl;
    const int c0 = cg * 12;

    if (n < N) {
        float acc[12];
#pragma unroll
        for (int j = 0; j < 12; ++j) acc[j] = 0.f;

        for (int k4 = 0; k4 < F / 4; ++k4) {
            float4 xv = *reinterpret_cast<const float4*>(&xs[nl][k4 * 4]);
#pragma unroll
            for (int j = 0; j < 12; ++j) {
                float4 wv = *reinterpret_cast<const float4*>(&Ws[c0 + j][k4 * 4]);
                acc[j] += xv.x * wv.x + xv.y * wv.y + xv.z * wv.z + xv.w * wv.w;
            }
        }
#pragma unroll
        for (int j = 0; j < 12; j += 4) {
            float4 v = make_float4(acc[j], acc[j + 1], acc[j + 2], acc[j + 3]);
            *reinterpret_cast<float4*>(&feat[(size_t)n * C + c0 + j]) = v;
        }
        float pl[H] = {0.f, 0.f, 0.f}, pr[H] = {0.f, 0.f, 0.f};
#pragma unroll
        for (int j = 0; j < 12; ++j) {
            int c = c0 + j;
            int h = c >> 4;
            pl[h] += acc[j] * attn_l[c];
            pr[h] += acc[j] * attn_r[c];
        }
#pragma unroll
        for (int h = 0; h < H; ++h) {
            pl[h] += __shfl_xor(pl[h], 1);
            pl[h] += __shfl_xor(pl[h], 2);
            pr[h] += __shfl_xor(pr[h], 1);
            pr[h] += __shfl_xor(pr[h], 2);
        }
        if (cg == 0) {
#pragma unroll
            for (int h = 0; h < H; ++h) {
                el[(size_t)n * H + h] = pl[h];
                er[(size_t)n * H + h] = pr[h];
            }
        }
    }
}

// ---------------- K2a: degree histogram -----------------------------------
__global__ __launch_bounds__(256) void hist_kernel(
    const int* __restrict__ dst, int* __restrict__ deg, int E)
{
    int e = blockIdx.x * blockDim.x + threadIdx.x;
    if (e < E) atomicAdd(&deg[dst[e]], 1);
}

// ---------------- K2b: 3-phase grid-wide exclusive scan --------------------
// phase 1: per-block sums (256 elems/block)
__global__ __launch_bounds__(256) void scan_part_kernel(
    const int* __restrict__ deg, int* __restrict__ partials, int N)
{
    __shared__ int red[256];
    const int tid = threadIdx.x;
    int i = blockIdx.x * 256 + tid;
    red[tid] = (i < N) ? deg[i] : 0;
    __syncthreads();
#pragma unroll
    for (int d = 128; d > 0; d >>= 1) {
        if (tid < d) red[tid] += red[tid + d];
        __syncthreads();
    }
    if (tid == 0) partials[blockIdx.x] = red[0];
}

// phase 2: single block exclusive-scans the partials (B <= 1024)
__global__ __launch_bounds__(1024) void scan_top_kernel(
    int* __restrict__ partials, int B)
{
    __shared__ int s[1024];
    const int tid = threadIdx.x;
    int v = (tid < B) ? partials[tid] : 0;
    s[tid] = v;
    __syncthreads();
    for (int d = 1; d < 1024; d <<= 1) {
        int t = (tid >= d) ? s[tid - d] : 0;
        __syncthreads();
        s[tid] += t;
        __syncthreads();
    }
    if (tid < B) partials[tid] = s[tid] - v;  // inclusive -> exclusive
}

// phase 3: per-block local exclusive scan + block offset -> off, cursor
__global__ __launch_bounds__(256) void scan_write_kernel(
    const int* __restrict__ deg, const int* __restrict__ partials,
    int* __restrict__ off, int* __restrict__ cursor, int N)
{
    __shared__ int s[256];
    const int tid = threadIdx.x;
    int i = blockIdx.x * 256 + tid;
    int v = (i < N) ? deg[i] : 0;
    s[tid] = v;
    __syncthreads();
#pragma unroll
    for (int d = 1; d < 256; d <<= 1) {
        int t = (tid >= d) ? s[tid - d] : 0;
        __syncthreads();
        s[tid] += t;
        __syncthreads();
    }
    int excl = s[tid] - v + partials[blockIdx.x];
    if (i < N) {
        off[i] = excl;
        cursor[i] = excl;
        if (i == N - 1) off[N] = excl + v;
    }
}

// ---------------- K2c: scatter src into CSR order --------------------------
__global__ __launch_bounds__(256) void scatter_kernel(
    const int* __restrict__ src, const int* __restrict__ dst,
    int* __restrict__ cursor, int* __restrict__ srcs, int E)
{
    int e = blockIdx.x * blockDim.x + threadIdx.x;
    if (e >= E) return;
    int d = dst[e];
    int pos = atomicAdd(&cursor[d], 1);
    srcs[pos] = src[e];
}

// ---------------- K3: node-parallel gather + softmax + blend ---------------
__global__ __launch_bounds__(256) void gather_kernel(
    const int* __restrict__ off, const int* __restrict__ srcs,
    const float* __restrict__ el, const float* __restrict__ er,
    const float* __restrict__ feat, const float* __restrict__ lin,
    float* __restrict__ out, int N)
{
    const int tid = threadIdx.x;
    const int nl = tid >> 2;
    const int cg = tid & 3;
    const int n = blockIdx.x * 64 + nl;
    if (n >= N) return;
    const int c0 = cg * 12;

    float ern[H];
#pragma unroll
    for (int h = 0; h < H; ++h) ern[h] = er[(size_t)n * H + h];

    float acc[12];
#pragma unroll
    for (int j = 0; j < 12; ++j) acc[j] = 0.f;
    float den[H] = {0.f, 0.f, 0.f};

    const int start = off[n];
    const int end = off[n + 1];
    for (int e = start; e < end; ++e) {
        int s = srcs[e];
        float w[H];
#pragma unroll
        for (int h = 0; h < H; ++h) {
            float t = el[(size_t)s * H + h] + ern[h];
            t = t > 0.f ? t : NEG_SLOPE * t;
            w[h] = __expf(t);
            den[h] += w[h];
        }
        const float* fs = &feat[(size_t)s * C + c0];
#pragma unroll
        for (int j = 0; j < 12; j += 4) {
            float4 f = *reinterpret_cast<const float4*>(&fs[j]);
            float wh = w[(c0 + j) >> 4];
            acc[j + 0] += wh * f.x;
            acc[j + 1] += wh * f.y;
            acc[j + 2] += wh * f.z;
            acc[j + 3] += wh * f.w;
        }
    }

    const float l = lin[n];
    const float om = 1.f - l;
#pragma unroll
    for (int j = 0; j < 12; j += 4) {
        int h = (c0 + j) >> 4;
        float inv = den[h] > 0.f ? 1.f / den[h] : 0.f;
        float4 f = *reinterpret_cast<const float4*>(&feat[(size_t)n * C + c0 + j]);
        float4 o;
        o.x = om * (acc[j + 0] * inv) + l * f.x;
        o.y = om * (acc[j + 1] * inv) + l * f.y;
        o.z = om * (acc[j + 2] * inv) + l * f.z;
        o.w = om * (acc[j + 3] * inv) + l * f.w;
        *reinterpret_cast<float4*>(&out[(size_t)n * C + c0 + j]) = o;
    }
}

extern "C" void kernel_launch(void* const* d_in, const int* in_sizes, int n_in,
                              void* d_out, int out_size, void* d_ws, size_t ws_size,
                              hipStream_t stream)
{
    const float* x      = (const float*)d_in[0];
    const float* W      = (const float*)d_in[1];
    const float* attn_l = (const float*)d_in[2];
    const float* attn_r = (const float*)d_in[3];
    const float* lin    = (const float*)d_in[4];
    const int*   src    = (const int*)d_in[5];
    const int*   dst    = (const int*)d_in[6];
    const int N = in_sizes[4];
    const int E = in_sizes[5];
    float* out = (float*)d_out;

    const int SB = (N + 255) / 256;  // scan blocks (391 <= 1024)

    // workspace layout
    float* feat     = (float*)d_ws;                  // N*C
    float* el       = feat + (size_t)N * C;          // N*H
    float* er       = el   + (size_t)N * H;          // N*H
    int*   deg      = (int*)(er + (size_t)N * H);    // N      (zeroed)
    int*   off      = deg + N;                       // N+1
    int*   cursor   = off + N + 1;                   // N
    int*   partials = cursor + N;                    // SB
    int*   srcs     = partials + 1024;               // E

    hipMemsetAsync(deg, 0, (size_t)N * sizeof(int), stream);

    feat_el_er_kernel<<<(N + 63) / 64, 256, 0, stream>>>(
        x, W, attn_l, attn_r, feat, el, er, N);
    hist_kernel<<<(E + 255) / 256, 256, 0, stream>>>(dst, deg, E);
    scan_part_kernel<<<SB, 256, 0, stream>>>(deg, partials, N);
    scan_top_kernel<<<1, 1024, 0, stream>>>(partials, SB);
    scan_write_kernel<<<SB, 256, 0, stream>>>(deg, partials, off, cursor, N);
    scatter_kernel<<<(E + 255) / 256, 256, 0, stream>>>(src, dst, cursor, srcs, E);
    gather_kernel<<<(N + 63) / 64, 256, 0, stream>>>(
        off, srcs, el, er, feat, lin, out, N);
}

// Round 6
// 338.952 us; speedup vs baseline: 12.8601x; 1.2238x over previous
//
#include <hip/hip_runtime.h>

// GAT layer: N=100000 nodes, E=1600000 edges, F=128, H=3 heads, D=16.
// CSR built WITHOUT a with-return-atomic scatter: hist assigns per-edge rank,
// scatter is a pure fire-and-forget store.
constexpr int F = 128;
constexpr int H = 3;
constexpr int D = 16;
constexpr int C = H * D;  // 48
#define NEG_SLOPE 0.2f

// ---------------- K1: feat = x @ W^T ; el/er = <feat, attn_l/r> per head ----
__global__ __launch_bounds__(256) void feat_el_er_kernel(
    const float* __restrict__ x, const float* __restrict__ W,
    const float* __restrict__ attn_l, const float* __restrict__ attn_r,
    float* __restrict__ feat, float* __restrict__ el, float* __restrict__ er,
    int N)
{
    __shared__ float xs[64][F + 4];
    __shared__ float Ws[C][F + 4];
    const int tid = threadIdx.x;
    const int base = blockIdx.x * 64;

    for (int i = tid; i < C * F / 4; i += 256) {
        int c = i >> 5, k4 = i & 31;
        float4 v = *reinterpret_cast<const float4*>(&W[c * F + k4 * 4]);
        *reinterpret_cast<float4*>(&Ws[c][k4 * 4]) = v;
    }
    for (int i = tid; i < 64 * F / 4; i += 256) {
        int nl = i >> 5, k4 = i & 31;
        int n = base + nl;
        if (n < N) {
            float4 v = *reinterpret_cast<const float4*>(&x[(size_t)n * F + k4 * 4]);
            *reinterpret_cast<float4*>(&xs[nl][k4 * 4]) = v;
        }
    }
    __syncthreads();

    const int nl = tid >> 2;
    const int cg = tid & 3;
    const int n = base + nl;
    const int c0 = cg * 12;

    if (n < N) {
        float acc[12];
#pragma unroll
        for (int j = 0; j < 12; ++j) acc[j] = 0.f;

        for (int k4 = 0; k4 < F / 4; ++k4) {
            float4 xv = *reinterpret_cast<const float4*>(&xs[nl][k4 * 4]);
#pragma unroll
            for (int j = 0; j < 12; ++j) {
                float4 wv = *reinterpret_cast<const float4*>(&Ws[c0 + j][k4 * 4]);
                acc[j] += xv.x * wv.x + xv.y * wv.y + xv.z * wv.z + xv.w * wv.w;
            }
        }
#pragma unroll
        for (int j = 0; j < 12; j += 4) {
            float4 v = make_float4(acc[j], acc[j + 1], acc[j + 2], acc[j + 3]);
            *reinterpret_cast<float4*>(&feat[(size_t)n * C + c0 + j]) = v;
        }
        float pl[H] = {0.f, 0.f, 0.f}, pr[H] = {0.f, 0.f, 0.f};
#pragma unroll
        for (int j = 0; j < 12; ++j) {
            int c = c0 + j;
            int h = c >> 4;
            pl[h] += acc[j] * attn_l[c];
            pr[h] += acc[j] * attn_r[c];
        }
#pragma unroll
        for (int h = 0; h < H; ++h) {
            pl[h] += __shfl_xor(pl[h], 1);
            pl[h] += __shfl_xor(pl[h], 2);
            pr[h] += __shfl_xor(pr[h], 1);
            pr[h] += __shfl_xor(pr[h], 2);
        }
        if (cg == 0) {
#pragma unroll
            for (int h = 0; h < H; ++h) {
                el[(size_t)n * H + h] = pl[h];
                er[(size_t)n * H + h] = pr[h];
            }
        }
    }
}

// ---------------- K2a: degree histogram + per-edge rank --------------------
__global__ __launch_bounds__(256) void hist_pos_kernel(
    const int* __restrict__ dst, int* __restrict__ deg,
    int* __restrict__ pos, int E)
{
    int e = blockIdx.x * blockDim.x + threadIdx.x;
    if (e < E) pos[e] = atomicAdd(&deg[dst[e]], 1);
}

// ---------------- K2b: 3-phase grid-wide exclusive scan --------------------
__global__ __launch_bounds__(256) void scan_part_kernel(
    const int* __restrict__ deg, int* __restrict__ partials, int N)
{
    __shared__ int red[256];
    const int tid = threadIdx.x;
    int i = blockIdx.x * 256 + tid;
    red[tid] = (i < N) ? deg[i] : 0;
    __syncthreads();
#pragma unroll
    for (int d = 128; d > 0; d >>= 1) {
        if (tid < d) red[tid] += red[tid + d];
        __syncthreads();
    }
    if (tid == 0) partials[blockIdx.x] = red[0];
}

__global__ __launch_bounds__(1024) void scan_top_kernel(
    int* __restrict__ partials, int B)
{
    __shared__ int s[1024];
    const int tid = threadIdx.x;
    int v = (tid < B) ? partials[tid] : 0;
    s[tid] = v;
    __syncthreads();
    for (int d = 1; d < 1024; d <<= 1) {
        int t = (tid >= d) ? s[tid - d] : 0;
        __syncthreads();
        s[tid] += t;
        __syncthreads();
    }
    if (tid < B) partials[tid] = s[tid] - v;  // inclusive -> exclusive
}

__global__ __launch_bounds__(256) void scan_write_kernel(
    const int* __restrict__ deg, const int* __restrict__ partials,
    int* __restrict__ off, int N)
{
    __shared__ int s[256];
    const int tid = threadIdx.x;
    int i = blockIdx.x * 256 + tid;
    int v = (i < N) ? deg[i] : 0;
    s[tid] = v;
    __syncthreads();
#pragma unroll
    for (int d = 1; d < 256; d <<= 1) {
        int t = (tid >= d) ? s[tid - d] : 0;
        __syncthreads();
        s[tid] += t;
        __syncthreads();
    }
    int excl = s[tid] - v + partials[blockIdx.x];
    if (i < N) {
        off[i] = excl;
        if (i == N - 1) off[N] = excl + v;
    }
}

// ---------------- K2c: atomic-free scatter into CSR order ------------------
// srcs[off[d] + rank] = src ; pure store, no result needed -> fire & forget.
__global__ __launch_bounds__(256) void scatter_kernel(
    const int* __restrict__ src, const int* __restrict__ dst,
    const int* __restrict__ pos, const int* __restrict__ off,
    int* __restrict__ srcs, int E)
{
    int e = blockIdx.x * blockDim.x + threadIdx.x;
    if (e >= E) return;
    int d = dst[e];
    srcs[off[d] + pos[e]] = src[e];
}

// ---------------- K3: node-parallel gather + softmax + blend ---------------
// 4 lanes/node, 12 channels each; unrolled x2 for memory-level parallelism.
__global__ __launch_bounds__(256) void gather_kernel(
    const int* __restrict__ off, const int* __restrict__ srcs,
    const float* __restrict__ el, const float* __restrict__ er,
    const float* __restrict__ feat, const float* __restrict__ lin,
    float* __restrict__ out, int N)
{
    const int tid = threadIdx.x;
    const int nl = tid >> 2;
    const int cg = tid & 3;
    const int n = blockIdx.x * 64 + nl;
    if (n >= N) return;
    const int c0 = cg * 12;

    float ern[H];
#pragma unroll
    for (int h = 0; h < H; ++h) ern[h] = er[(size_t)n * H + h];

    float acc[12];
#pragma unroll
    for (int j = 0; j < 12; ++j) acc[j] = 0.f;
    float den[H] = {0.f, 0.f, 0.f};

    const int start = off[n];
    const int end = off[n + 1];
    int e = start;
    for (; e + 2 <= end; e += 2) {
        int s0 = srcs[e];
        int s1 = srcs[e + 1];
        float w0[H], w1[H];
#pragma unroll
        for (int h = 0; h < H; ++h) {
            float t0 = el[(size_t)s0 * H + h] + ern[h];
            float t1 = el[(size_t)s1 * H + h] + ern[h];
            t0 = t0 > 0.f ? t0 : NEG_SLOPE * t0;
            t1 = t1 > 0.f ? t1 : NEG_SLOPE * t1;
            w0[h] = __expf(t0);
            w1[h] = __expf(t1);
            den[h] += w0[h] + w1[h];
        }
        const float* fs0 = &feat[(size_t)s0 * C + c0];
        const float* fs1 = &feat[(size_t)s1 * C + c0];
#pragma unroll
        for (int j = 0; j < 12; j += 4) {
            float4 f0 = *reinterpret_cast<const float4*>(&fs0[j]);
            float4 f1 = *reinterpret_cast<const float4*>(&fs1[j]);
            float wh0 = w0[(c0 + j) >> 4];
            float wh1 = w1[(c0 + j) >> 4];
            acc[j + 0] += wh0 * f0.x + wh1 * f1.x;
            acc[j + 1] += wh0 * f0.y + wh1 * f1.y;
            acc[j + 2] += wh0 * f0.z + wh1 * f1.z;
            acc[j + 3] += wh0 * f0.w + wh1 * f1.w;
        }
    }
    if (e < end) {
        int s = srcs[e];
        float w[H];
#pragma unroll
        for (int h = 0; h < H; ++h) {
            float t = el[(size_t)s * H + h] + ern[h];
            t = t > 0.f ? t : NEG_SLOPE * t;
            w[h] = __expf(t);
            den[h] += w[h];
        }
        const float* fs = &feat[(size_t)s * C + c0];
#pragma unroll
        for (int j = 0; j < 12; j += 4) {
            float4 f = *reinterpret_cast<const float4*>(&fs[j]);
            float wh = w[(c0 + j) >> 4];
            acc[j + 0] += wh * f.x;
            acc[j + 1] += wh * f.y;
            acc[j + 2] += wh * f.z;
            acc[j + 3] += wh * f.w;
        }
    }

    const float l = lin[n];
    const float om = 1.f - l;
#pragma unroll
    for (int j = 0; j < 12; j += 4) {
        int h = (c0 + j) >> 4;
        float inv = den[h] > 0.f ? 1.f / den[h] : 0.f;
        float4 f = *reinterpret_cast<const float4*>(&feat[(size_t)n * C + c0 + j]);
        float4 o;
        o.x = om * (acc[j + 0] * inv) + l * f.x;
        o.y = om * (acc[j + 1] * inv) + l * f.y;
        o.z = om * (acc[j + 2] * inv) + l * f.z;
        o.w = om * (acc[j + 3] * inv) + l * f.w;
        *reinterpret_cast<float4*>(&out[(size_t)n * C + c0 + j]) = o;
    }
}

extern "C" void kernel_launch(void* const* d_in, const int* in_sizes, int n_in,
                              void* d_out, int out_size, void* d_ws, size_t ws_size,
                              hipStream_t stream)
{
    const float* x      = (const float*)d_in[0];
    const float* W      = (const float*)d_in[1];
    const float* attn_l = (const float*)d_in[2];
    const float* attn_r = (const float*)d_in[3];
    const float* lin    = (const float*)d_in[4];
    const int*   src    = (const int*)d_in[5];
    const int*   dst    = (const int*)d_in[6];
    const int N = in_sizes[4];
    const int E = in_sizes[5];
    float* out = (float*)d_out;

    const int SB = (N + 255) / 256;  // scan blocks (391 <= 1024)

    // workspace layout
    float* feat     = (float*)d_ws;                  // N*C
    float* el       = feat + (size_t)N * C;          // N*H
    float* er       = el   + (size_t)N * H;          // N*H
    int*   deg      = (int*)(er + (size_t)N * H);    // N      (zeroed)
    int*   off      = deg + N;                       // N+1
    int*   partials = off + N + 1;                   // 1024
    int*   pos      = partials + 1024;               // E
    int*   srcs     = pos + E;                       // E

    hipMemsetAsync(deg, 0, (size_t)N * sizeof(int), stream);

    feat_el_er_kernel<<<(N + 63) / 64, 256, 0, stream>>>(
        x, W, attn_l, attn_r, feat, el, er, N);
    hist_pos_kernel<<<(E + 255) / 256, 256, 0, stream>>>(dst, deg, pos, E);
    scan_part_kernel<<<SB, 256, 0, stream>>>(deg, partials, N);
    scan_top_kernel<<<1, 1024, 0, stream>>>(partials, SB);
    scan_write_kernel<<<SB, 256, 0, stream>>>(deg, partials, off, N);
    scatter_kernel<<<(E + 255) / 256, 256, 0, stream>>>(src, dst, pos, off, srcs, E);
    gather_kernel<<<(N + 63) / 64, 256, 0, stream>>>(
        off, srcs, el, er, feat, lin, out, N);
}

// Round 7
// 290.340 us; speedup vs baseline: 15.0133x; 1.1674x over previous
//
#include <hip/hip_runtime.h>

// GAT layer: N=100000 nodes, E=1600000 edges, F=128, H=3 heads, D=16.
// CSR built without with-return-atomic scatter; gather reads a PACKED 128B
// row per src node: 48 bf16 feat channels (96B) + fp32 el[3] (12B) + pad.
// -> exactly 2 cache lines per edge instead of 3-4.
constexpr int F = 128;
constexpr int H = 3;
constexpr int D = 16;
constexpr int C = H * D;   // 48
constexpr int RS = 32;     // packed row stride in floats (128 B)
#define NEG_SLOPE 0.2f

__device__ __forceinline__ unsigned short f2bf(float f) {
    unsigned u = __float_as_uint(f);
    u += 0x7fffu + ((u >> 16) & 1u);   // round-to-nearest-even
    return (unsigned short)(u >> 16);
}
__device__ __forceinline__ float bflo(unsigned u) { return __uint_as_float(u << 16); }
__device__ __forceinline__ float bfhi(unsigned u) { return __uint_as_float(u & 0xffff0000u); }

// ---------------- K1: feat = x @ W^T ; writes packed row + er ---------------
__global__ __launch_bounds__(256) void feat_el_er_kernel(
    const float* __restrict__ x, const float* __restrict__ W,
    const float* __restrict__ attn_l, const float* __restrict__ attn_r,
    float* __restrict__ packed, float* __restrict__ er, int N)
{
    __shared__ float xs[64][F + 4];
    __shared__ float Ws[C][F + 4];
    const int tid = threadIdx.x;
    const int base = blockIdx.x * 64;

    for (int i = tid; i < C * F / 4; i += 256) {
        int c = i >> 5, k4 = i & 31;
        float4 v = *reinterpret_cast<const float4*>(&W[c * F + k4 * 4]);
        *reinterpret_cast<float4*>(&Ws[c][k4 * 4]) = v;
    }
    for (int i = tid; i < 64 * F / 4; i += 256) {
        int nl = i >> 5, k4 = i & 31;
        int n = base + nl;
        if (n < N) {
            float4 v = *reinterpret_cast<const float4*>(&x[(size_t)n * F + k4 * 4]);
            *reinterpret_cast<float4*>(&xs[nl][k4 * 4]) = v;
        }
    }
    __syncthreads();

    const int nl = tid >> 2;
    const int cg = tid & 3;
    const int n = base + nl;
    const int c0 = cg * 12;

    if (n < N) {
        float acc[12];
#pragma unroll
        for (int j = 0; j < 12; ++j) acc[j] = 0.f;

        for (int k4 = 0; k4 < F / 4; ++k4) {
            float4 xv = *reinterpret_cast<const float4*>(&xs[nl][k4 * 4]);
#pragma unroll
            for (int j = 0; j < 12; ++j) {
                float4 wv = *reinterpret_cast<const float4*>(&Ws[c0 + j][k4 * 4]);
                acc[j] += xv.x * wv.x + xv.y * wv.y + xv.z * wv.z + xv.w * wv.w;
            }
        }
        // pack 12 channels as bf16 pairs -> 6 uints -> 3 uint2 stores
        unsigned up[6];
#pragma unroll
        for (int i = 0; i < 6; ++i)
            up[i] = (unsigned)f2bf(acc[2 * i]) | ((unsigned)f2bf(acc[2 * i + 1]) << 16);
        uint2* prow = reinterpret_cast<uint2*>(packed + (size_t)n * RS + cg * 6);
        prow[0] = make_uint2(up[0], up[1]);
        prow[1] = make_uint2(up[2], up[3]);
        prow[2] = make_uint2(up[4], up[5]);

        // el/er partials over this lane's 12 channels
        float pl[H] = {0.f, 0.f, 0.f}, pr[H] = {0.f, 0.f, 0.f};
#pragma unroll
        for (int j = 0; j < 12; ++j) {
            int c = c0 + j;
            int h = c >> 4;
            pl[h] += acc[j] * attn_l[c];
            pr[h] += acc[j] * attn_r[c];
        }
#pragma unroll
        for (int h = 0; h < H; ++h) {
            pl[h] += __shfl_xor(pl[h], 1);
            pl[h] += __shfl_xor(pl[h], 2);
            pr[h] += __shfl_xor(pr[h], 1);
            pr[h] += __shfl_xor(pr[h], 2);
        }
        if (cg == 0) {
            *reinterpret_cast<float4*>(packed + (size_t)n * RS + 24) =
                make_float4(pl[0], pl[1], pl[2], 0.f);
            er[(size_t)n * H + 0] = pr[0];
            er[(size_t)n * H + 1] = pr[1];
            er[(size_t)n * H + 2] = pr[2];
        }
    }
}

// ---------------- K2a: degree histogram + per-edge rank --------------------
__global__ __launch_bounds__(256) void hist_pos_kernel(
    const int* __restrict__ dst, int* __restrict__ deg,
    int* __restrict__ pos, int E)
{
    int e = blockIdx.x * blockDim.x + threadIdx.x;
    if (e < E) pos[e] = atomicAdd(&deg[dst[e]], 1);
}

// ---------------- K2b: 3-phase grid-wide exclusive scan --------------------
__global__ __launch_bounds__(256) void scan_part_kernel(
    const int* __restrict__ deg, int* __restrict__ partials, int N)
{
    __shared__ int red[256];
    const int tid = threadIdx.x;
    int i = blockIdx.x * 256 + tid;
    red[tid] = (i < N) ? deg[i] : 0;
    __syncthreads();
#pragma unroll
    for (int d = 128; d > 0; d >>= 1) {
        if (tid < d) red[tid] += red[tid + d];
        __syncthreads();
    }
    if (tid == 0) partials[blockIdx.x] = red[0];
}

__global__ __launch_bounds__(1024) void scan_top_kernel(
    int* __restrict__ partials, int B)
{
    __shared__ int s[1024];
    const int tid = threadIdx.x;
    int v = (tid < B) ? partials[tid] : 0;
    s[tid] = v;
    __syncthreads();
    for (int d = 1; d < 1024; d <<= 1) {
        int t = (tid >= d) ? s[tid - d] : 0;
        __syncthreads();
        s[tid] += t;
        __syncthreads();
    }
    if (tid < B) partials[tid] = s[tid] - v;  // inclusive -> exclusive
}

__global__ __launch_bounds__(256) void scan_write_kernel(
    const int* __restrict__ deg, const int* __restrict__ partials,
    int* __restrict__ off, int N)
{
    __shared__ int s[256];
    const int tid = threadIdx.x;
    int i = blockIdx.x * 256 + tid;
    int v = (i < N) ? deg[i] : 0;
    s[tid] = v;
    __syncthreads();
#pragma unroll
    for (int d = 1; d < 256; d <<= 1) {
        int t = (tid >= d) ? s[tid - d] : 0;
        __syncthreads();
        s[tid] += t;
        __syncthreads();
    }
    int excl = s[tid] - v + partials[blockIdx.x];
    if (i < N) {
        off[i] = excl;
        if (i == N - 1) off[N] = excl + v;
    }
}

// ---------------- K2c: atomic-free scatter into CSR order ------------------
__global__ __launch_bounds__(256) void scatter_kernel(
    const int* __restrict__ src, const int* __restrict__ dst,
    const int* __restrict__ pos, const int* __restrict__ off,
    int* __restrict__ srcs, int E)
{
    int e = blockIdx.x * blockDim.x + threadIdx.x;
    if (e >= E) return;
    int d = dst[e];
    srcs[off[d] + pos[e]] = src[e];
}

// ---------------- K3: node-parallel gather on packed rows ------------------
// 4 lanes/node, 12 channels each. Per lane, per edge: 3x uint2 (bf16 feat)
// + 1x float4 (el, same 2nd line of the row) -> 2 cache lines per edge total.
// Each lane only computes exp for the 1-2 heads its channels belong to.
__global__ __launch_bounds__(256) void gather_kernel(
    const int* __restrict__ off, const int* __restrict__ srcs,
    const float* __restrict__ packed, const float* __restrict__ er,
    const float* __restrict__ lin, float* __restrict__ out, int N)
{
    const int tid = threadIdx.x;
    const int nl = tid >> 2;
    const int cg = tid & 3;
    const int n = blockIdx.x * 64 + nl;
    if (n >= N) return;
    const int cbase = cg * 12;
    const int hA = cbase >> 4;
    const int hB = (cbase + 11) >> 4;
    const int jb0 = 16 - (cbase & 15);
    const int jb = jb0 > 12 ? 12 : jb0;          // j < jb -> head hA, else hB
    const bool twoHeads = (hB != hA);

    const float ernA = er[(size_t)n * H + hA];
    const float ernB = er[(size_t)n * H + hB];

    float acc[12];
#pragma unroll
    for (int j = 0; j < 12; ++j) acc[j] = 0.f;
    float denA = 0.f, denB = 0.f;

    const int start = off[n];
    const int end = off[n + 1];
    int e = start;

#define EDGE_BODY(SRC)                                                         \
    {                                                                          \
        const float* row = packed + (size_t)(SRC) * RS;                        \
        float4 ev = *reinterpret_cast<const float4*>(row + 24);                \
        float elA = hA == 0 ? ev.x : (hA == 1 ? ev.y : ev.z);                  \
        float tA = elA + ernA;                                                 \
        tA = tA > 0.f ? tA : NEG_SLOPE * tA;                                   \
        float wA = __expf(tA);                                                 \
        denA += wA;                                                            \
        float wB = wA;                                                         \
        if (twoHeads) {                                                        \
            float elB = hB == 1 ? ev.y : ev.z;                                 \
            float tB = elB + ernB;                                             \
            tB = tB > 0.f ? tB : NEG_SLOPE * tB;                               \
            wB = __expf(tB);                                                   \
            denB += wB;                                                        \
        }                                                                      \
        const uint2* fp = reinterpret_cast<const uint2*>(row + cg * 6);        \
        uint2 q0 = fp[0], q1 = fp[1], q2 = fp[2];                              \
        unsigned uu[6] = {q0.x, q0.y, q1.x, q1.y, q2.x, q2.y};                 \
        _Pragma("unroll")                                                      \
        for (int i = 0; i < 6; ++i) {                                          \
            float wlo = (2 * i < jb) ? wA : wB;                                \
            float whi = (2 * i + 1 < jb) ? wA : wB;                            \
            acc[2 * i]     += wlo * bflo(uu[i]);                               \
            acc[2 * i + 1] += whi * bfhi(uu[i]);                               \
        }                                                                      \
    }

    for (; e + 2 <= end; e += 2) {
        int s0 = srcs[e];
        int s1 = srcs[e + 1];
        EDGE_BODY(s0);
        EDGE_BODY(s1);
    }
    if (e < end) {
        int s0 = srcs[e];
        EDGE_BODY(s0);
    }
#undef EDGE_BODY

    const float l = lin[n];
    const float om = 1.f - l;
    float invA = denA > 0.f ? 1.f / denA : 0.f;   // deg-0 node -> msg = 0
    float invB = twoHeads ? (denB > 0.f ? 1.f / denB : 0.f) : invA;

    // own feats (bf16) for the blend term
    const float* myrow = packed + (size_t)n * RS;
    const uint2* mp = reinterpret_cast<const uint2*>(myrow + cg * 6);
    uint2 m0 = mp[0], m1 = mp[1], m2 = mp[2];
    unsigned mu[6] = {m0.x, m0.y, m1.x, m1.y, m2.x, m2.y};

    float o[12];
#pragma unroll
    for (int i = 0; i < 6; ++i) {
        float ilo = (2 * i < jb) ? invA : invB;
        float ihi = (2 * i + 1 < jb) ? invA : invB;
        o[2 * i]     = om * (acc[2 * i] * ilo) + l * bflo(mu[i]);
        o[2 * i + 1] = om * (acc[2 * i + 1] * ihi) + l * bfhi(mu[i]);
    }
#pragma unroll
    for (int j = 0; j < 12; j += 4) {
        *reinterpret_cast<float4*>(&out[(size_t)n * C + cbase + j]) =
            make_float4(o[j], o[j + 1], o[j + 2], o[j + 3]);
    }
}

extern "C" void kernel_launch(void* const* d_in, const int* in_sizes, int n_in,
                              void* d_out, int out_size, void* d_ws, size_t ws_size,
                              hipStream_t stream)
{
    const float* x      = (const float*)d_in[0];
    const float* W      = (const float*)d_in[1];
    const float* attn_l = (const float*)d_in[2];
    const float* attn_r = (const float*)d_in[3];
    const float* lin    = (const float*)d_in[4];
    const int*   src    = (const int*)d_in[5];
    const int*   dst    = (const int*)d_in[6];
    const int N = in_sizes[4];
    const int E = in_sizes[5];
    float* out = (float*)d_out;

    const int SB = (N + 255) / 256;  // scan blocks (391 <= 1024)

    // workspace layout (packed first -> 128B row alignment)
    float* packed   = (float*)d_ws;                  // N*RS (128B rows)
    float* er       = packed + (size_t)N * RS;       // N*H
    int*   deg      = (int*)(er + (size_t)N * H);    // N      (zeroed)
    int*   off      = deg + N;                       // N+1
    int*   partials = off + N + 1;                   // 1024
    int*   pos      = partials + 1024;               // E
    int*   srcs     = pos + E;                       // E

    hipMemsetAsync(deg, 0, (size_t)N * sizeof(int), stream);

    feat_el_er_kernel<<<(N + 63) / 64, 256, 0, stream>>>(
        x, W, attn_l, attn_r, packed, er, N);
    hist_pos_kernel<<<(E + 255) / 256, 256, 0, stream>>>(dst, deg, pos, E);
    scan_part_kernel<<<SB, 256, 0, stream>>>(deg, partials, N);
    scan_top_kernel<<<1, 1024, 0, stream>>>(partials, SB);
    scan_write_kernel<<<SB, 256, 0, stream>>>(deg, partials, off, N);
    scatter_kernel<<<(E + 255) / 256, 256, 0, stream>>>(src, dst, pos, off, srcs, E);
    gather_kernel<<<(N + 63) / 64, 256, 0, stream>>>(
        off, srcs, packed, er, lin, out, N);
}

// Round 8
// 287.853 us; speedup vs baseline: 15.1429x; 1.0086x over previous
//
#include <hip/hip_runtime.h>

// GAT layer: N=100000 nodes, E=1600000 edges, F=128, H=3 heads, D=16.
// CSR without with-return-atomic scatter; packed 128B row per node
// (48 bf16 feat + fp32 el[3]); feat GEMM fused with the atomic-bound
// histogram pass (independent work, heterogeneous grid) to hide the
// ~23.5 Gatomic/s device-atomic throughput wall under compute.
constexpr int F = 128;
constexpr int H = 3;
constexpr int D = 16;
constexpr int C = H * D;   // 48
constexpr int RS = 32;     // packed row stride in floats (128 B)
#define NEG_SLOPE 0.2f

__device__ __forceinline__ unsigned short f2bf(float f) {
    unsigned u = __float_as_uint(f);
    u += 0x7fffu + ((u >> 16) & 1u);   // round-to-nearest-even
    return (unsigned short)(u >> 16);
}
__device__ __forceinline__ float bflo(unsigned u) { return __uint_as_float(u << 16); }
__device__ __forceinline__ float bfhi(unsigned u) { return __uint_as_float(u & 0xffff0000u); }

// ---------------- K1: fused [hist+rank | feat GEMM] ------------------------
// blocks [0, histB): pos[e] = rank of edge within its dst (4 edges/thread,
//                    4 independent atomics in flight).
// blocks [histB, histB+featB): feat = x @ W^T, packed bf16 row + el + er.
__global__ __launch_bounds__(256) void fused_feat_hist_kernel(
    const float* __restrict__ x, const float* __restrict__ W,
    const float* __restrict__ attn_l, const float* __restrict__ attn_r,
    float* __restrict__ packed, float* __restrict__ er,
    const int* __restrict__ dst, int* __restrict__ deg, int* __restrict__ pos,
    int N, int E, int histB)
{
    __shared__ float xs[64][F + 4];
    __shared__ float Ws[C][F + 4];
    const int tid = threadIdx.x;

    if ((int)blockIdx.x < histB) {
        const int base = blockIdx.x * 1024 + tid;
#pragma unroll
        for (int k = 0; k < 4; ++k) {
            int e = base + k * 256;
            if (e < E) pos[e] = atomicAdd(&deg[dst[e]], 1);
        }
        return;
    }

    const int base = (blockIdx.x - histB) * 64;

    for (int i = tid; i < C * F / 4; i += 256) {
        int c = i >> 5, k4 = i & 31;
        float4 v = *reinterpret_cast<const float4*>(&W[c * F + k4 * 4]);
        *reinterpret_cast<float4*>(&Ws[c][k4 * 4]) = v;
    }
    for (int i = tid; i < 64 * F / 4; i += 256) {
        int nl = i >> 5, k4 = i & 31;
        int n = base + nl;
        if (n < N) {
            float4 v = *reinterpret_cast<const float4*>(&x[(size_t)n * F + k4 * 4]);
            *reinterpret_cast<float4*>(&xs[nl][k4 * 4]) = v;
        }
    }
    __syncthreads();

    const int nl = tid >> 2;
    const int cg = tid & 3;
    const int n = base + nl;
    const int c0 = cg * 12;

    if (n < N) {
        float acc[12];
#pragma unroll
        for (int j = 0; j < 12; ++j) acc[j] = 0.f;

        for (int k4 = 0; k4 < F / 4; ++k4) {
            float4 xv = *reinterpret_cast<const float4*>(&xs[nl][k4 * 4]);
#pragma unroll
            for (int j = 0; j < 12; ++j) {
                float4 wv = *reinterpret_cast<const float4*>(&Ws[c0 + j][k4 * 4]);
                acc[j] += xv.x * wv.x + xv.y * wv.y + xv.z * wv.z + xv.w * wv.w;
            }
        }
        // pack 12 channels as bf16 pairs -> 6 uints -> 3 uint2 stores
        unsigned up[6];
#pragma unroll
        for (int i = 0; i < 6; ++i)
            up[i] = (unsigned)f2bf(acc[2 * i]) | ((unsigned)f2bf(acc[2 * i + 1]) << 16);
        uint2* prow = reinterpret_cast<uint2*>(packed + (size_t)n * RS + cg * 6);
        prow[0] = make_uint2(up[0], up[1]);
        prow[1] = make_uint2(up[2], up[3]);
        prow[2] = make_uint2(up[4], up[5]);

        // el/er partials over this lane's 12 channels
        float pl[H] = {0.f, 0.f, 0.f}, pr[H] = {0.f, 0.f, 0.f};
#pragma unroll
        for (int j = 0; j < 12; ++j) {
            int c = c0 + j;
            int h = c >> 4;
            pl[h] += acc[j] * attn_l[c];
            pr[h] += acc[j] * attn_r[c];
        }
#pragma unroll
        for (int h = 0; h < H; ++h) {
            pl[h] += __shfl_xor(pl[h], 1);
            pl[h] += __shfl_xor(pl[h], 2);
            pr[h] += __shfl_xor(pr[h], 1);
            pr[h] += __shfl_xor(pr[h], 2);
        }
        if (cg == 0) {
            *reinterpret_cast<float4*>(packed + (size_t)n * RS + 24) =
                make_float4(pl[0], pl[1], pl[2], 0.f);
            er[(size_t)n * H + 0] = pr[0];
            er[(size_t)n * H + 1] = pr[1];
            er[(size_t)n * H + 2] = pr[2];
        }
    }
}

// ---------------- K2b: 3-phase grid-wide exclusive scan --------------------
__global__ __launch_bounds__(256) void scan_part_kernel(
    const int* __restrict__ deg, int* __restrict__ partials, int N)
{
    __shared__ int red[256];
    const int tid = threadIdx.x;
    int i = blockIdx.x * 256 + tid;
    red[tid] = (i < N) ? deg[i] : 0;
    __syncthreads();
#pragma unroll
    for (int d = 128; d > 0; d >>= 1) {
        if (tid < d) red[tid] += red[tid + d];
        __syncthreads();
    }
    if (tid == 0) partials[blockIdx.x] = red[0];
}

__global__ __launch_bounds__(1024) void scan_top_kernel(
    int* __restrict__ partials, int B)
{
    __shared__ int s[1024];
    const int tid = threadIdx.x;
    int v = (tid < B) ? partials[tid] : 0;
    s[tid] = v;
    __syncthreads();
    for (int d = 1; d < 1024; d <<= 1) {
        int t = (tid >= d) ? s[tid - d] : 0;
        __syncthreads();
        s[tid] += t;
        __syncthreads();
    }
    if (tid < B) partials[tid] = s[tid] - v;  // inclusive -> exclusive
}

__global__ __launch_bounds__(256) void scan_write_kernel(
    const int* __restrict__ deg, const int* __restrict__ partials,
    int* __restrict__ off, int N)
{
    __shared__ int s[256];
    const int tid = threadIdx.x;
    int i = blockIdx.x * 256 + tid;
    int v = (i < N) ? deg[i] : 0;
    s[tid] = v;
    __syncthreads();
#pragma unroll
    for (int d = 1; d < 256; d <<= 1) {
        int t = (tid >= d) ? s[tid - d] : 0;
        __syncthreads();
        s[tid] += t;
        __syncthreads();
    }
    int excl = s[tid] - v + partials[blockIdx.x];
    if (i < N) {
        off[i] = excl;
        if (i == N - 1) off[N] = excl + v;
    }
}

// ---------------- K2c: atomic-free scatter into CSR order ------------------
__global__ __launch_bounds__(256) void scatter_kernel(
    const int* __restrict__ src, const int* __restrict__ dst,
    const int* __restrict__ pos, const int* __restrict__ off,
    int* __restrict__ srcs, int E)
{
    int e = blockIdx.x * blockDim.x + threadIdx.x;
    if (e >= E) return;
    int d = dst[e];
    srcs[off[d] + pos[e]] = src[e];
}

// ---------------- K3: node-parallel gather on packed rows ------------------
__global__ __launch_bounds__(256) void gather_kernel(
    const int* __restrict__ off, const int* __restrict__ srcs,
    const float* __restrict__ packed, const float* __restrict__ er,
    const float* __restrict__ lin, float* __restrict__ out, int N)
{
    const int tid = threadIdx.x;
    const int nl = tid >> 2;
    const int cg = tid & 3;
    const int n = blockIdx.x * 64 + nl;
    if (n >= N) return;
    const int cbase = cg * 12;
    const int hA = cbase >> 4;
    const int hB = (cbase + 11) >> 4;
    const int jb0 = 16 - (cbase & 15);
    const int jb = jb0 > 12 ? 12 : jb0;          // j < jb -> head hA, else hB
    const bool twoHeads = (hB != hA);

    const float ernA = er[(size_t)n * H + hA];
    const float ernB = er[(size_t)n * H + hB];

    float acc[12];
#pragma unroll
    for (int j = 0; j < 12; ++j) acc[j] = 0.f;
    float denA = 0.f, denB = 0.f;

    const int start = off[n];
    const int end = off[n + 1];
    int e = start;

#define EDGE_BODY(SRC)                                                         \
    {                                                                          \
        const float* row = packed + (size_t)(SRC) * RS;                        \
        float4 ev = *reinterpret_cast<const float4*>(row + 24);                \
        float elA = hA == 0 ? ev.x : (hA == 1 ? ev.y : ev.z);                  \
        float tA = elA + ernA;                                                 \
        tA = tA > 0.f ? tA : NEG_SLOPE * tA;                                   \
        float wA = __expf(tA);                                                 \
        denA += wA;                                                            \
        float wB = wA;                                                         \
        if (twoHeads) {                                                        \
            float elB = hB == 1 ? ev.y : ev.z;                                 \
            float tB = elB + ernB;                                             \
            tB = tB > 0.f ? tB : NEG_SLOPE * tB;                               \
            wB = __expf(tB);                                                   \
            denB += wB;                                                        \
        }                                                                      \
        const uint2* fp = reinterpret_cast<const uint2*>(row + cg * 6);        \
        uint2 q0 = fp[0], q1 = fp[1], q2 = fp[2];                              \
        unsigned uu[6] = {q0.x, q0.y, q1.x, q1.y, q2.x, q2.y};                 \
        _Pragma("unroll")                                                      \
        for (int i = 0; i < 6; ++i) {                                          \
            float wlo = (2 * i < jb) ? wA : wB;                                \
            float whi = (2 * i + 1 < jb) ? wA : wB;                            \
            acc[2 * i]     += wlo * bflo(uu[i]);                               \
            acc[2 * i + 1] += whi * bfhi(uu[i]);                               \
        }                                                                      \
    }

    for (; e + 2 <= end; e += 2) {
        int s0 = srcs[e];
        int s1 = srcs[e + 1];
        EDGE_BODY(s0);
        EDGE_BODY(s1);
    }
    if (e < end) {
        int s0 = srcs[e];
        EDGE_BODY(s0);
    }
#undef EDGE_BODY

    const float l = lin[n];
    const float om = 1.f - l;
    float invA = denA > 0.f ? 1.f / denA : 0.f;   // deg-0 node -> msg = 0
    float invB = twoHeads ? (denB > 0.f ? 1.f / denB : 0.f) : invA;

    // own feats (bf16) for the blend term
    const float* myrow = packed + (size_t)n * RS;
    const uint2* mp = reinterpret_cast<const uint2*>(myrow + cg * 6);
    uint2 m0 = mp[0], m1 = mp[1], m2 = mp[2];
    unsigned mu[6] = {m0.x, m0.y, m1.x, m1.y, m2.x, m2.y};

    float o[12];
#pragma unroll
    for (int i = 0; i < 6; ++i) {
        float ilo = (2 * i < jb) ? invA : invB;
        float ihi = (2 * i + 1 < jb) ? invA : invB;
        o[2 * i]     = om * (acc[2 * i] * ilo) + l * bflo(mu[i]);
        o[2 * i + 1] = om * (acc[2 * i + 1] * ihi) + l * bfhi(mu[i]);
    }
#pragma unroll
    for (int j = 0; j < 12; j += 4) {
        *reinterpret_cast<float4*>(&out[(size_t)n * C + cbase + j]) =
            make_float4(o[j], o[j + 1], o[j + 2], o[j + 3]);
    }
}

extern "C" void kernel_launch(void* const* d_in, const int* in_sizes, int n_in,
                              void* d_out, int out_size, void* d_ws, size_t ws_size,
                              hipStream_t stream)
{
    const float* x      = (const float*)d_in[0];
    const float* W      = (const float*)d_in[1];
    const float* attn_l = (const float*)d_in[2];
    const float* attn_r = (const float*)d_in[3];
    const float* lin    = (const float*)d_in[4];
    const int*   src    = (const int*)d_in[5];
    const int*   dst    = (const int*)d_in[6];
    const int N = in_sizes[4];
    const int E = in_sizes[5];
    float* out = (float*)d_out;

    const int SB    = (N + 255) / 256;    // scan blocks (391 <= 1024)
    const int histB = (E + 1023) / 1024;  // 1563
    const int featB = (N + 63) / 64;      // 1563

    // workspace layout (packed first -> 128B row alignment)
    float* packed   = (float*)d_ws;                  // N*RS (128B rows)
    float* er       = packed + (size_t)N * RS;       // N*H
    int*   deg      = (int*)(er + (size_t)N * H);    // N      (zeroed)
    int*   off      = deg + N;                       // N+1
    int*   partials = off + N + 1;                   // 1024
    int*   pos      = partials + 1024;               // E
    int*   srcs     = pos + E;                       // E

    hipMemsetAsync(deg, 0, (size_t)N * sizeof(int), stream);

    fused_feat_hist_kernel<<<histB + featB, 256, 0, stream>>>(
        x, W, attn_l, attn_r, packed, er, dst, deg, pos, N, E, histB);
    scan_part_kernel<<<SB, 256, 0, stream>>>(deg, partials, N);
    scan_top_kernel<<<1, 1024, 0, stream>>>(partials, SB);
    scan_write_kernel<<<SB, 256, 0, stream>>>(deg, partials, off, N);
    scatter_kernel<<<(E + 255) / 256, 256, 0, stream>>>(src, dst, pos, off, srcs, E);
    gather_kernel<<<(N + 63) / 64, 256, 0, stream>>>(
        off, srcs, packed, er, lin, out, N);
}

// Round 9
// 255.673 us; speedup vs baseline: 17.0489x; 1.1259x over previous
//
#include <hip/hip_runtime.h>

// GAT layer: N=100000 nodes, E=1600000 edges, F=128, H=3 heads, D=16.
// CSR without with-return-atomic scatter; packed 128B row per node
// (48 bf16 feat + fp32 el[3]). Fused [hist | feat] kernel with
// INTERLEAVED block roles and Ws-only LDS (25 KB) so atomic-stalled hist
// waves and VALU-bound feat waves co-reside on every CU.
constexpr int F = 128;
constexpr int H = 3;
constexpr int D = 16;
constexpr int C = H * D;   // 48
constexpr int RS = 32;     // packed row stride in floats (128 B)
#define NEG_SLOPE 0.2f

__device__ __forceinline__ unsigned short f2bf(float f) {
    unsigned u = __float_as_uint(f);
    u += 0x7fffu + ((u >> 16) & 1u);   // round-to-nearest-even
    return (unsigned short)(u >> 16);
}
__device__ __forceinline__ float bflo(unsigned u) { return __uint_as_float(u << 16); }
__device__ __forceinline__ float bfhi(unsigned u) { return __uint_as_float(u & 0xffff0000u); }

// ---------------- K1: fused [hist+rank | feat GEMM], interleaved ----------
// even blocks: hist role (1024 edges each, 4 independent atomics in flight)
// odd blocks:  feat role (64 nodes each; x read direct-global, W in LDS)
__global__ __launch_bounds__(256) void fused_feat_hist_kernel(
    const float* __restrict__ x, const float* __restrict__ W,
    const float* __restrict__ attn_l, const float* __restrict__ attn_r,
    float* __restrict__ packed, float* __restrict__ er,
    const int* __restrict__ dst, int* __restrict__ deg, int* __restrict__ pos,
    int N, int E, int histB, int featB)
{
    __shared__ float Ws[C][F + 4];   // 25.3 KB — the ONLY LDS in this kernel
    const int tid = threadIdx.x;
    const int bid = blockIdx.x;

    // role assignment: interleave while both roles remain, then tail
    const int nPair = 2 * (histB < featB ? histB : featB);
    bool isHist;
    int idx;
    if (bid < nPair) {
        isHist = !(bid & 1);
        idx = bid >> 1;
    } else {
        int r = bid - nPair;
        if (histB > featB) { isHist = true;  idx = featB + r; }
        else               { isHist = false; idx = histB + r; }
    }

    if (isHist) {
        const int base = idx * 1024 + tid;
#pragma unroll
        for (int k = 0; k < 4; ++k) {
            int e = base + k * 256;
            if (e < E) pos[e] = atomicAdd(&deg[dst[e]], 1);
        }
        return;
    }

    // ---- feat role ----
    for (int i = tid; i < C * F / 4; i += 256) {
        int c = i >> 5, k4 = i & 31;
        float4 v = *reinterpret_cast<const float4*>(&W[c * F + k4 * 4]);
        *reinterpret_cast<float4*>(&Ws[c][k4 * 4]) = v;
    }
    __syncthreads();

    const int nl = tid >> 2;
    const int cg = tid & 3;
    const int n = idx * 64 + nl;
    const int c0 = cg * 12;

    if (n < N) {
        const float* xrow = &x[(size_t)n * F];
        float acc[12];
#pragma unroll
        for (int j = 0; j < 12; ++j) acc[j] = 0.f;

        for (int k4 = 0; k4 < F / 4; ++k4) {
            float4 xv = *reinterpret_cast<const float4*>(&xrow[k4 * 4]); // 4 lanes same addr -> broadcast
#pragma unroll
            for (int j = 0; j < 12; ++j) {
                float4 wv = *reinterpret_cast<const float4*>(&Ws[c0 + j][k4 * 4]);
                acc[j] += xv.x * wv.x + xv.y * wv.y + xv.z * wv.z + xv.w * wv.w;
            }
        }
        // pack 12 channels as bf16 pairs -> 6 uints -> 3 uint2 stores
        unsigned up[6];
#pragma unroll
        for (int i = 0; i < 6; ++i)
            up[i] = (unsigned)f2bf(acc[2 * i]) | ((unsigned)f2bf(acc[2 * i + 1]) << 16);
        uint2* prow = reinterpret_cast<uint2*>(packed + (size_t)n * RS + cg * 6);
        prow[0] = make_uint2(up[0], up[1]);
        prow[1] = make_uint2(up[2], up[3]);
        prow[2] = make_uint2(up[4], up[5]);

        // el/er partials over this lane's 12 channels
        float pl[H] = {0.f, 0.f, 0.f}, pr[H] = {0.f, 0.f, 0.f};
#pragma unroll
        for (int j = 0; j < 12; ++j) {
            int c = c0 + j;
            int h = c >> 4;
            pl[h] += acc[j] * attn_l[c];
            pr[h] += acc[j] * attn_r[c];
        }
#pragma unroll
        for (int h = 0; h < H; ++h) {
            pl[h] += __shfl_xor(pl[h], 1);
            pl[h] += __shfl_xor(pl[h], 2);
            pr[h] += __shfl_xor(pr[h], 1);
            pr[h] += __shfl_xor(pr[h], 2);
        }
        if (cg == 0) {
            *reinterpret_cast<float4*>(packed + (size_t)n * RS + 24) =
                make_float4(pl[0], pl[1], pl[2], 0.f);
            er[(size_t)n * H + 0] = pr[0];
            er[(size_t)n * H + 1] = pr[1];
            er[(size_t)n * H + 2] = pr[2];
        }
    }
}

// ---------------- K2b: 3-phase grid-wide exclusive scan --------------------
__global__ __launch_bounds__(256) void scan_part_kernel(
    const int* __restrict__ deg, int* __restrict__ partials, int N)
{
    __shared__ int red[256];
    const int tid = threadIdx.x;
    int i = blockIdx.x * 256 + tid;
    red[tid] = (i < N) ? deg[i] : 0;
    __syncthreads();
#pragma unroll
    for (int d = 128; d > 0; d >>= 1) {
        if (tid < d) red[tid] += red[tid + d];
        __syncthreads();
    }
    if (tid == 0) partials[blockIdx.x] = red[0];
}

__global__ __launch_bounds__(1024) void scan_top_kernel(
    int* __restrict__ partials, int B)
{
    __shared__ int s[1024];
    const int tid = threadIdx.x;
    int v = (tid < B) ? partials[tid] : 0;
    s[tid] = v;
    __syncthreads();
    for (int d = 1; d < 1024; d <<= 1) {
        int t = (tid >= d) ? s[tid - d] : 0;
        __syncthreads();
        s[tid] += t;
        __syncthreads();
    }
    if (tid < B) partials[tid] = s[tid] - v;  // inclusive -> exclusive
}

__global__ __launch_bounds__(256) void scan_write_kernel(
    const int* __restrict__ deg, const int* __restrict__ partials,
    int* __restrict__ off, int N)
{
    __shared__ int s[256];
    const int tid = threadIdx.x;
    int i = blockIdx.x * 256 + tid;
    int v = (i < N) ? deg[i] : 0;
    s[tid] = v;
    __syncthreads();
#pragma unroll
    for (int d = 1; d < 256; d <<= 1) {
        int t = (tid >= d) ? s[tid - d] : 0;
        __syncthreads();
        s[tid] += t;
        __syncthreads();
    }
    int excl = s[tid] - v + partials[blockIdx.x];
    if (i < N) {
        off[i] = excl;
        if (i == N - 1) off[N] = excl + v;
    }
}

// ---------------- K2c: atomic-free scatter into CSR order ------------------
__global__ __launch_bounds__(256) void scatter_kernel(
    const int* __restrict__ src, const int* __restrict__ dst,
    const int* __restrict__ pos, const int* __restrict__ off,
    int* __restrict__ srcs, int E)
{
    int e = blockIdx.x * blockDim.x + threadIdx.x;
    if (e >= E) return;
    int d = dst[e];
    srcs[off[d] + pos[e]] = src[e];
}

// ---------------- K3: node-parallel gather on packed rows ------------------
__global__ __launch_bounds__(256) void gather_kernel(
    const int* __restrict__ off, const int* __restrict__ srcs,
    const float* __restrict__ packed, const float* __restrict__ er,
    const float* __restrict__ lin, float* __restrict__ out, int N)
{
    const int tid = threadIdx.x;
    const int nl = tid >> 2;
    const int cg = tid & 3;
    const int n = blockIdx.x * 64 + nl;
    if (n >= N) return;
    const int cbase = cg * 12;
    const int hA = cbase >> 4;
    const int hB = (cbase + 11) >> 4;
    const int jb0 = 16 - (cbase & 15);
    const int jb = jb0 > 12 ? 12 : jb0;          // j < jb -> head hA, else hB
    const bool twoHeads = (hB != hA);

    const float ernA = er[(size_t)n * H + hA];
    const float ernB = er[(size_t)n * H + hB];

    float acc[12];
#pragma unroll
    for (int j = 0; j < 12; ++j) acc[j] = 0.f;
    float denA = 0.f, denB = 0.f;

    const int start = off[n];
    const int end = off[n + 1];
    int e = start;

#define EDGE_BODY(SRC)                                                         \
    {                                                                          \
        const float* row = packed + (size_t)(SRC) * RS;                        \
        float4 ev = *reinterpret_cast<const float4*>(row + 24);                \
        float elA = hA == 0 ? ev.x : (hA == 1 ? ev.y : ev.z);                  \
        float tA = elA + ernA;                                                 \
        tA = tA > 0.f ? tA : NEG_SLOPE * tA;                                   \
        float wA = __expf(tA);                                                 \
        denA += wA;                                                            \
        float wB = wA;                                                         \
        if (twoHeads) {                                                        \
            float elB = hB == 1 ? ev.y : ev.z;                                 \
            float tB = elB + ernB;                                             \
            tB = tB > 0.f ? tB : NEG_SLOPE * tB;                               \
            wB = __expf(tB);                                                   \
            denB += wB;                                                        \
        }                                                                      \
        const uint2* fp = reinterpret_cast<const uint2*>(row + cg * 6);        \
        uint2 q0 = fp[0], q1 = fp[1], q2 = fp[2];                              \
        unsigned uu[6] = {q0.x, q0.y, q1.x, q1.y, q2.x, q2.y};                 \
        _Pragma("unroll")                                                      \
        for (int i = 0; i < 6; ++i) {                                          \
            float wlo = (2 * i < jb) ? wA : wB;                                \
            float whi = (2 * i + 1 < jb) ? wA : wB;                            \
            acc[2 * i]     += wlo * bflo(uu[i]);                               \
            acc[2 * i + 1] += whi * bfhi(uu[i]);                               \
        }                                                                      \
    }

    for (; e + 2 <= end; e += 2) {
        int s0 = srcs[e];
        int s1 = srcs[e + 1];
        EDGE_BODY(s0);
        EDGE_BODY(s1);
    }
    if (e < end) {
        int s0 = srcs[e];
        EDGE_BODY(s0);
    }
#undef EDGE_BODY

    const float l = lin[n];
    const float om = 1.f - l;
    float invA = denA > 0.f ? 1.f / denA : 0.f;   // deg-0 node -> msg = 0
    float invB = twoHeads ? (denB > 0.f ? 1.f / denB : 0.f) : invA;

    // own feats (bf16) for the blend term
    const float* myrow = packed + (size_t)n * RS;
    const uint2* mp = reinterpret_cast<const uint2*>(myrow + cg * 6);
    uint2 m0 = mp[0], m1 = mp[1], m2 = mp[2];
    unsigned mu[6] = {m0.x, m0.y, m1.x, m1.y, m2.x, m2.y};

    float o[12];
#pragma unroll
    for (int i = 0; i < 6; ++i) {
        float ilo = (2 * i < jb) ? invA : invB;
        float ihi = (2 * i + 1 < jb) ? invA : invB;
        o[2 * i]     = om * (acc[2 * i] * ilo) + l * bflo(mu[i]);
        o[2 * i + 1] = om * (acc[2 * i + 1] * ihi) + l * bfhi(mu[i]);
    }
#pragma unroll
    for (int j = 0; j < 12; j += 4) {
        *reinterpret_cast<float4*>(&out[(size_t)n * C + cbase + j]) =
            make_float4(o[j], o[j + 1], o[j + 2], o[j + 3]);
    }
}

extern "C" void kernel_launch(void* const* d_in, const int* in_sizes, int n_in,
                              void* d_out, int out_size, void* d_ws, size_t ws_size,
                              hipStream_t stream)
{
    const float* x      = (const float*)d_in[0];
    const float* W      = (const float*)d_in[1];
    const float* attn_l = (const float*)d_in[2];
    const float* attn_r = (const float*)d_in[3];
    const float* lin    = (const float*)d_in[4];
    const int*   src    = (const int*)d_in[5];
    const int*   dst    = (const int*)d_in[6];
    const int N = in_sizes[4];
    const int E = in_sizes[5];
    float* out = (float*)d_out;

    const int SB    = (N + 255) / 256;    // scan blocks (391 <= 1024)
    const int histB = (E + 1023) / 1024;  // 1563
    const int featB = (N + 63) / 64;      // 1563

    // workspace layout (packed first -> 128B row alignment)
    float* packed   = (float*)d_ws;                  // N*RS (128B rows)
    float* er       = packed + (size_t)N * RS;       // N*H
    int*   deg      = (int*)(er + (size_t)N * H);    // N      (zeroed)
    int*   off      = deg + N;                       // N+1
    int*   partials = off + N + 1;                   // 1024
    int*   pos      = partials + 1024;               // E
    int*   srcs     = pos + E;                       // E

    hipMemsetAsync(deg, 0, (size_t)N * sizeof(int), stream);

    fused_feat_hist_kernel<<<histB + featB, 256, 0, stream>>>(
        x, W, attn_l, attn_r, packed, er, dst, deg, pos, N, E, histB, featB);
    scan_part_kernel<<<SB, 256, 0, stream>>>(deg, partials, N);
    scan_top_kernel<<<1, 1024, 0, stream>>>(partials, SB);
    scan_write_kernel<<<SB, 256, 0, stream>>>(deg, partials, off, N);
    scatter_kernel<<<(E + 255) / 256, 256, 0, stream>>>(src, dst, pos, off, srcs, E);
    gather_kernel<<<(N + 63) / 64, 256, 0, stream>>>(
        off, srcs, packed, er, lin, out, N);
}

// Round 10
// 231.721 us; speedup vs baseline: 18.8112x; 1.1034x over previous
//
#include <hip/hip_runtime.h>

// GAT layer: N=100000 nodes, E=1600000 edges, F=128, H=3 heads, D=16.
// CSR built by two-level counting sort with LDS atomics ONLY (device-scope
// atomics write-through ~32B/op and cap at ~750 GB/s -> 68us wall; LDS
// atomics don't). Packed 128B row per node (48 bf16 feat + fp32 el[3]).
constexpr int F = 128;
constexpr int H = 3;
constexpr int D = 16;
constexpr int C = H * D;    // 48
constexpr int RS = 32;      // packed row stride in floats (128 B)
constexpr int BKT = 256;    // dst values per coarse bucket (dst >> 8)
constexpr int CHUNK = 2048; // edges per count/scatter block
constexpr int MAXNB = 512;  // LDS bound for bucket counters (NB=391)
#define NEG_SLOPE 0.2f

__device__ __forceinline__ unsigned short f2bf(float f) {
    unsigned u = __float_as_uint(f);
    u += 0x7fffu + ((u >> 16) & 1u);   // round-to-nearest-even
    return (unsigned short)(u >> 16);
}
__device__ __forceinline__ float bflo(unsigned u) { return __uint_as_float(u << 16); }
__device__ __forceinline__ float bfhi(unsigned u) { return __uint_as_float(u & 0xffff0000u); }

// ---------------- K1: feat = x @ W^T -> packed bf16 row + el + er ----------
// 64 nodes/block, 4 lanes/node; W in LDS (25 KB), x direct-global broadcast.
__global__ __launch_bounds__(256) void feat_kernel(
    const float* __restrict__ x, const float* __restrict__ W,
    const float* __restrict__ attn_l, const float* __restrict__ attn_r,
    float* __restrict__ packed, float* __restrict__ er, int N)
{
    __shared__ float Ws[C][F + 4];
    const int tid = threadIdx.x;

    for (int i = tid; i < C * F / 4; i += 256) {
        int c = i >> 5, k4 = i & 31;
        float4 v = *reinterpret_cast<const float4*>(&W[c * F + k4 * 4]);
        *reinterpret_cast<float4*>(&Ws[c][k4 * 4]) = v;
    }
    __syncthreads();

    const int nl = tid >> 2;
    const int cg = tid & 3;
    const int n = blockIdx.x * 64 + nl;
    const int c0 = cg * 12;
    if (n >= N) return;

    const float* xrow = &x[(size_t)n * F];
    float acc[12];
#pragma unroll
    for (int j = 0; j < 12; ++j) acc[j] = 0.f;

    for (int k4 = 0; k4 < F / 4; ++k4) {
        float4 xv = *reinterpret_cast<const float4*>(&xrow[k4 * 4]); // 4 lanes same addr -> broadcast
#pragma unroll
        for (int j = 0; j < 12; ++j) {
            float4 wv = *reinterpret_cast<const float4*>(&Ws[c0 + j][k4 * 4]);
            acc[j] += xv.x * wv.x + xv.y * wv.y + xv.z * wv.z + xv.w * wv.w;
        }
    }
    unsigned up[6];
#pragma unroll
    for (int i = 0; i < 6; ++i)
        up[i] = (unsigned)f2bf(acc[2 * i]) | ((unsigned)f2bf(acc[2 * i + 1]) << 16);
    uint2* prow = reinterpret_cast<uint2*>(packed + (size_t)n * RS + cg * 6);
    prow[0] = make_uint2(up[0], up[1]);
    prow[1] = make_uint2(up[2], up[3]);
    prow[2] = make_uint2(up[4], up[5]);

    float pl[H] = {0.f, 0.f, 0.f}, pr[H] = {0.f, 0.f, 0.f};
#pragma unroll
    for (int j = 0; j < 12; ++j) {
        int c = c0 + j;
        int h = c >> 4;
        pl[h] += acc[j] * attn_l[c];
        pr[h] += acc[j] * attn_r[c];
    }
#pragma unroll
    for (int h = 0; h < H; ++h) {
        pl[h] += __shfl_xor(pl[h], 1);
        pl[h] += __shfl_xor(pl[h], 2);
        pr[h] += __shfl_xor(pr[h], 1);
        pr[h] += __shfl_xor(pr[h], 2);
    }
    if (cg == 0) {
        *reinterpret_cast<float4*>(packed + (size_t)n * RS + 24) =
            make_float4(pl[0], pl[1], pl[2], 0.f);
        er[(size_t)n * H + 0] = pr[0];
        er[(size_t)n * H + 1] = pr[1];
        er[(size_t)n * H + 2] = pr[2];
    }
}

// ---------------- P1: per-block coarse-bucket histogram (LDS atomics) ------
__global__ __launch_bounds__(256) void p1_count_kernel(
    const int* __restrict__ dst, int* __restrict__ counts, int E, int EB, int NB)
{
    __shared__ int hist[MAXNB];
    const int tid = threadIdx.x;
    for (int b = tid; b < NB; b += 256) hist[b] = 0;
    __syncthreads();
    const int base = blockIdx.x * CHUNK;
#pragma unroll
    for (int k = 0; k < CHUNK / 256; ++k) {
        int e = base + k * 256 + tid;
        if (e < E) atomicAdd(&hist[dst[e] >> 8], 1);
    }
    __syncthreads();
    for (int b = tid; b < NB; b += 256)
        counts[(size_t)b * EB + blockIdx.x] = hist[b];
}

// ---------------- scan of counts[NB*EB]: 3-phase, 1024 elems/block ---------
__global__ __launch_bounds__(256) void scanA_kernel(
    const int* __restrict__ a, int* __restrict__ partials, int T)
{
    __shared__ int red[256];
    const int tid = threadIdx.x;
    const int base = blockIdx.x * 1024;
    int s = 0;
#pragma unroll
    for (int k = 0; k < 4; ++k) {
        int i = base + k * 256 + tid;
        if (i < T) s += a[i];
    }
    red[tid] = s;
    __syncthreads();
#pragma unroll
    for (int d = 128; d > 0; d >>= 1) {
        if (tid < d) red[tid] += red[tid + d];
        __syncthreads();
    }
    if (tid == 0) partials[blockIdx.x] = red[0];
}

__global__ __launch_bounds__(512) void scanB_kernel(int* __restrict__ partials, int B)
{
    __shared__ int s[512];
    const int tid = threadIdx.x;
    int v = (tid < B) ? partials[tid] : 0;
    s[tid] = v;
    __syncthreads();
    for (int d = 1; d < 512; d <<= 1) {
        int t = (tid >= d) ? s[tid - d] : 0;
        __syncthreads();
        s[tid] += t;
        __syncthreads();
    }
    if (tid < B) partials[tid] = s[tid] - v;  // inclusive -> exclusive
}

__global__ __launch_bounds__(256) void scanC_kernel(
    int* __restrict__ a, const int* __restrict__ partials, int T)
{
    __shared__ int s[256];
    const int tid = threadIdx.x;
    const int idx0 = blockIdx.x * 1024 + tid * 4;  // thread owns 4 contiguous
    int e0 = 0, e1 = 0, e2 = 0, e3 = 0;
    if (idx0     < T) e0 = a[idx0];
    if (idx0 + 1 < T) e1 = a[idx0 + 1];
    if (idx0 + 2 < T) e2 = a[idx0 + 2];
    if (idx0 + 3 < T) e3 = a[idx0 + 3];
    int ls = e0 + e1 + e2 + e3;
    s[tid] = ls;
    __syncthreads();
    for (int d = 1; d < 256; d <<= 1) {
        int t = (tid >= d) ? s[tid - d] : 0;
        __syncthreads();
        s[tid] += t;
        __syncthreads();
    }
    int ex = s[tid] - ls + partials[blockIdx.x];
    if (idx0     < T) a[idx0]     = ex;
    if (idx0 + 1 < T) a[idx0 + 1] = ex + e0;
    if (idx0 + 2 < T) a[idx0 + 2] = ex + e0 + e1;
    if (idx0 + 3 < T) a[idx0 + 3] = ex + e0 + e1 + e2;
}

// ---------------- P3: bucket-major scatter of (src,dst) pairs --------------
__global__ __launch_bounds__(256) void p3_scatter_kernel(
    const int* __restrict__ src, const int* __restrict__ dst,
    const int* __restrict__ counts, uint2* __restrict__ pairs,
    int E, int EB, int NB)
{
    __shared__ int cur[MAXNB];
    const int tid = threadIdx.x;
    for (int b = tid; b < NB; b += 256)
        cur[b] = counts[(size_t)b * EB + blockIdx.x];  // scanned base for (b, blk)
    __syncthreads();
    const int base = blockIdx.x * CHUNK;
#pragma unroll
    for (int k = 0; k < CHUNK / 256; ++k) {
        int e = base + k * 256 + tid;
        if (e < E) {
            int d = dst[e];
            int p = atomicAdd(&cur[d >> 8], 1);   // LDS atomic
            pairs[p] = make_uint2((unsigned)src[e], (unsigned)d);
        }
    }
}

// ---------------- P4: in-bucket refine -> off + final srcs -----------------
// one block per bucket; 256 LDS counters (one dst value each).
__global__ __launch_bounds__(256) void p4_refine_kernel(
    const uint2* __restrict__ pairs, const int* __restrict__ counts,
    int* __restrict__ off, int* __restrict__ srcs,
    int N, int E, int EB, int NB)
{
    __shared__ int cnt[BKT];
    __shared__ int s[BKT];
    __shared__ int pref[BKT];
    const int tid = threadIdx.x;
    const int b = blockIdx.x;
    const int start = counts[(size_t)b * EB];
    const int end = (b == NB - 1) ? E : counts[(size_t)(b + 1) * EB];

    cnt[tid] = 0;
    __syncthreads();
    for (int e = start + tid; e < end; e += 256)
        atomicAdd(&cnt[pairs[e].y & (BKT - 1)], 1);
    __syncthreads();

    int v = cnt[tid];
    s[tid] = v;
    __syncthreads();
    for (int d = 1; d < 256; d <<= 1) {
        int t = (tid >= d) ? s[tid - d] : 0;
        __syncthreads();
        s[tid] += t;
        __syncthreads();
    }
    int ex = s[tid] - v;
    pref[tid] = ex;
    int dg = b * BKT + tid;
    if (dg <= N) off[dg] = start + ex;   // dg==N (last bucket) -> off[N]=E
    __syncthreads();

    for (int e = start + tid; e < end; e += 256) {
        uint2 pr = pairs[e];
        int d = pr.y & (BKT - 1);
        int slot = start + atomicAdd(&pref[d], 1);  // LDS atomic
        srcs[slot] = (int)pr.x;
    }
}

// ---------------- K3: node-parallel gather on packed rows ------------------
__global__ __launch_bounds__(256) void gather_kernel(
    const int* __restrict__ off, const int* __restrict__ srcs,
    const float* __restrict__ packed, const float* __restrict__ er,
    const float* __restrict__ lin, float* __restrict__ out, int N)
{
    const int tid = threadIdx.x;
    const int nl = tid >> 2;
    const int cg = tid & 3;
    const int n = blockIdx.x * 64 + nl;
    if (n >= N) return;
    const int cbase = cg * 12;
    const int hA = cbase >> 4;
    const int hB = (cbase + 11) >> 4;
    const int jb0 = 16 - (cbase & 15);
    const int jb = jb0 > 12 ? 12 : jb0;          // j < jb -> head hA, else hB
    const bool twoHeads = (hB != hA);

    const float ernA = er[(size_t)n * H + hA];
    const float ernB = er[(size_t)n * H + hB];

    float acc[12];
#pragma unroll
    for (int j = 0; j < 12; ++j) acc[j] = 0.f;
    float denA = 0.f, denB = 0.f;

    const int start = off[n];
    const int end = off[n + 1];
    int e = start;

#define EDGE_BODY(SRC)                                                         \
    {                                                                          \
        const float* row = packed + (size_t)(SRC) * RS;                        \
        float4 ev = *reinterpret_cast<const float4*>(row + 24);                \
        float elA = hA == 0 ? ev.x : (hA == 1 ? ev.y : ev.z);                  \
        float tA = elA + ernA;                                                 \
        tA = tA > 0.f ? tA : NEG_SLOPE * tA;                                   \
        float wA = __expf(tA);                                                 \
        denA += wA;                                                            \
        float wB = wA;                                                         \
        if (twoHeads) {                                                        \
            float elB = hB == 1 ? ev.y : ev.z;                                 \
            float tB = elB + ernB;                                             \
            tB = tB > 0.f ? tB : NEG_SLOPE * tB;                               \
            wB = __expf(tB);                                                   \
            denB += wB;                                                        \
        }                                                                      \
        const uint2* fp = reinterpret_cast<const uint2*>(row + cg * 6);        \
        uint2 q0 = fp[0], q1 = fp[1], q2 = fp[2];                              \
        unsigned uu[6] = {q0.x, q0.y, q1.x, q1.y, q2.x, q2.y};                 \
        _Pragma("unroll")                                                      \
        for (int i = 0; i < 6; ++i) {                                          \
            float wlo = (2 * i < jb) ? wA : wB;                                \
            float whi = (2 * i + 1 < jb) ? wA : wB;                            \
            acc[2 * i]     += wlo * bflo(uu[i]);                               \
            acc[2 * i + 1] += whi * bfhi(uu[i]);                               \
        }                                                                      \
    }

    for (; e + 2 <= end; e += 2) {
        int s0 = srcs[e];
        int s1 = srcs[e + 1];
        EDGE_BODY(s0);
        EDGE_BODY(s1);
    }
    if (e < end) {
        int s0 = srcs[e];
        EDGE_BODY(s0);
    }
#undef EDGE_BODY

    const float l = lin[n];
    const float om = 1.f - l;
    float invA = denA > 0.f ? 1.f / denA : 0.f;   // deg-0 node -> msg = 0
    float invB = twoHeads ? (denB > 0.f ? 1.f / denB : 0.f) : invA;

    const float* myrow = packed + (size_t)n * RS;
    const uint2* mp = reinterpret_cast<const uint2*>(myrow + cg * 6);
    uint2 m0 = mp[0], m1 = mp[1], m2 = mp[2];
    unsigned mu[6] = {m0.x, m0.y, m1.x, m1.y, m2.x, m2.y};

    float o[12];
#pragma unroll
    for (int i = 0; i < 6; ++i) {
        float ilo = (2 * i < jb) ? invA : invB;
        float ihi = (2 * i + 1 < jb) ? invA : invB;
        o[2 * i]     = om * (acc[2 * i] * ilo) + l * bflo(mu[i]);
        o[2 * i + 1] = om * (acc[2 * i + 1] * ihi) + l * bfhi(mu[i]);
    }
#pragma unroll
    for (int j = 0; j < 12; j += 4) {
        *reinterpret_cast<float4*>(&out[(size_t)n * C + cbase + j]) =
            make_float4(o[j], o[j + 1], o[j + 2], o[j + 3]);
    }
}

extern "C" void kernel_launch(void* const* d_in, const int* in_sizes, int n_in,
                              void* d_out, int out_size, void* d_ws, size_t ws_size,
                              hipStream_t stream)
{
    const float* x      = (const float*)d_in[0];
    const float* W      = (const float*)d_in[1];
    const float* attn_l = (const float*)d_in[2];
    const float* attn_r = (const float*)d_in[3];
    const float* lin    = (const float*)d_in[4];
    const int*   src    = (const int*)d_in[5];
    const int*   dst    = (const int*)d_in[6];
    const int N = in_sizes[4];
    const int E = in_sizes[5];
    float* out = (float*)d_out;

    const int NB = (N + BKT - 1) / BKT;        // 391 coarse buckets
    const int EB = (E + CHUNK - 1) / CHUNK;    // 782 edge blocks
    const int T  = NB * EB;                    // 305,762 counts
    const int SBlk = (T + 1023) / 1024;        // 299 scan blocks (<= 512)

    // workspace layout (packed first -> 128B row alignment; pairs 8B-aligned)
    float* packed   = (float*)d_ws;                     // N*RS floats
    float* er       = packed + (size_t)N * RS;          // N*H floats
    uint2* pairs    = (uint2*)(er + (size_t)N * H);     // E uint2 (offset 14MB, 8B-aligned)
    int*   counts   = (int*)(pairs + E);                // T ints
    int*   partials = counts + T;                       // 1024
    int*   off      = partials + 1024;                  // N+1
    int*   srcs     = off + (N + 1);                    // E
    // total ~35 MB; every word read is written by an earlier kernel (no memset)

    feat_kernel<<<(N + 63) / 64, 256, 0, stream>>>(
        x, W, attn_l, attn_r, packed, er, N);
    p1_count_kernel<<<EB, 256, 0, stream>>>(dst, counts, E, EB, NB);
    scanA_kernel<<<SBlk, 256, 0, stream>>>(counts, partials, T);
    scanB_kernel<<<1, 512, 0, stream>>>(partials, SBlk);
    scanC_kernel<<<SBlk, 256, 0, stream>>>(counts, partials, T);
    p3_scatter_kernel<<<EB, 256, 0, stream>>>(src, dst, counts, pairs, E, EB, NB);
    p4_refine_kernel<<<NB, 256, 0, stream>>>(pairs, counts, off, srcs, N, E, EB, NB);
    gather_kernel<<<(N + 63) / 64, 256, 0, stream>>>(
        off, srcs, packed, er, lin, out, N);
}

// Round 11
// 227.079 us; speedup vs baseline: 19.1957x; 1.0204x over previous
//
#include <hip/hip_runtime.h>

// GAT layer: N=100000 nodes, E=1600000 edges, F=128, H=3 heads, D=16.
// CSR via two-level LDS-atomic counting sort (no device atomics).
// Packed 128B row per node (48 bf16 feat + fp32 el[3]).
// Gather: 4-edge unroll, loads-first for 16 outstanding VMEM/lane.
constexpr int F = 128;
constexpr int H = 3;
constexpr int D = 16;
constexpr int C = H * D;    // 48
constexpr int RS = 32;      // packed row stride in floats (128 B)
constexpr int BKT = 256;    // dst values per coarse bucket (dst >> 8)
constexpr int CHUNK = 4096; // edges per count/scatter block
constexpr int MAXNB = 512;  // LDS bound for bucket counters (NB=391)
#define NEG_SLOPE 0.2f
// pairs packing: src in bits [0,17), dst&255 in bits [17,25). Requires N < 2^17.

__device__ __forceinline__ unsigned short f2bf(float f) {
    unsigned u = __float_as_uint(f);
    u += 0x7fffu + ((u >> 16) & 1u);   // round-to-nearest-even
    return (unsigned short)(u >> 16);
}
__device__ __forceinline__ float bflo(unsigned u) { return __uint_as_float(u << 16); }
__device__ __forceinline__ float bfhi(unsigned u) { return __uint_as_float(u & 0xffff0000u); }

// ---------------- K1: feat = x @ W^T -> packed bf16 row + el + er ----------
__global__ __launch_bounds__(256) void feat_kernel(
    const float* __restrict__ x, const float* __restrict__ W,
    const float* __restrict__ attn_l, const float* __restrict__ attn_r,
    float* __restrict__ packed, float* __restrict__ er, int N)
{
    __shared__ float Ws[C][F + 4];
    const int tid = threadIdx.x;

    for (int i = tid; i < C * F / 4; i += 256) {
        int c = i >> 5, k4 = i & 31;
        float4 v = *reinterpret_cast<const float4*>(&W[c * F + k4 * 4]);
        *reinterpret_cast<float4*>(&Ws[c][k4 * 4]) = v;
    }
    __syncthreads();

    const int nl = tid >> 2;
    const int cg = tid & 3;
    const int n = blockIdx.x * 64 + nl;
    const int c0 = cg * 12;
    if (n >= N) return;

    const float* xrow = &x[(size_t)n * F];
    float acc[12];
#pragma unroll
    for (int j = 0; j < 12; ++j) acc[j] = 0.f;

    for (int k4 = 0; k4 < F / 4; ++k4) {
        float4 xv = *reinterpret_cast<const float4*>(&xrow[k4 * 4]); // broadcast across 4 lanes
#pragma unroll
        for (int j = 0; j < 12; ++j) {
            float4 wv = *reinterpret_cast<const float4*>(&Ws[c0 + j][k4 * 4]);
            acc[j] += xv.x * wv.x + xv.y * wv.y + xv.z * wv.z + xv.w * wv.w;
        }
    }
    unsigned up[6];
#pragma unroll
    for (int i = 0; i < 6; ++i)
        up[i] = (unsigned)f2bf(acc[2 * i]) | ((unsigned)f2bf(acc[2 * i + 1]) << 16);
    uint2* prow = reinterpret_cast<uint2*>(packed + (size_t)n * RS + cg * 6);
    prow[0] = make_uint2(up[0], up[1]);
    prow[1] = make_uint2(up[2], up[3]);
    prow[2] = make_uint2(up[4], up[5]);

    float pl[H] = {0.f, 0.f, 0.f}, pr[H] = {0.f, 0.f, 0.f};
#pragma unroll
    for (int j = 0; j < 12; ++j) {
        int c = c0 + j;
        int h = c >> 4;
        pl[h] += acc[j] * attn_l[c];
        pr[h] += acc[j] * attn_r[c];
    }
#pragma unroll
    for (int h = 0; h < H; ++h) {
        pl[h] += __shfl_xor(pl[h], 1);
        pl[h] += __shfl_xor(pl[h], 2);
        pr[h] += __shfl_xor(pr[h], 1);
        pr[h] += __shfl_xor(pr[h], 2);
    }
    if (cg == 0) {
        *reinterpret_cast<float4*>(packed + (size_t)n * RS + 24) =
            make_float4(pl[0], pl[1], pl[2], 0.f);
        er[(size_t)n * H + 0] = pr[0];
        er[(size_t)n * H + 1] = pr[1];
        er[(size_t)n * H + 2] = pr[2];
    }
}

// ---------------- P1: per-block coarse-bucket histogram (LDS atomics) ------
__global__ __launch_bounds__(256) void p1_count_kernel(
    const int* __restrict__ dst, int* __restrict__ counts, int E, int EB, int NB)
{
    __shared__ int hist[MAXNB];
    const int tid = threadIdx.x;
    for (int b = tid; b < NB; b += 256) hist[b] = 0;
    __syncthreads();
    const int base = blockIdx.x * CHUNK;
#pragma unroll
    for (int k = 0; k < CHUNK / 256; ++k) {
        int e = base + k * 256 + tid;
        if (e < E) atomicAdd(&hist[dst[e] >> 8], 1);
    }
    __syncthreads();
    for (int b = tid; b < NB; b += 256)
        counts[(size_t)b * EB + blockIdx.x] = hist[b];
}

// ---------------- scan of counts[NB*EB]: 3-phase, 1024 elems/block ---------
__global__ __launch_bounds__(256) void scanA_kernel(
    const int* __restrict__ a, int* __restrict__ partials, int T)
{
    __shared__ int red[256];
    const int tid = threadIdx.x;
    const int base = blockIdx.x * 1024;
    int s = 0;
#pragma unroll
    for (int k = 0; k < 4; ++k) {
        int i = base + k * 256 + tid;
        if (i < T) s += a[i];
    }
    red[tid] = s;
    __syncthreads();
#pragma unroll
    for (int d = 128; d > 0; d >>= 1) {
        if (tid < d) red[tid] += red[tid + d];
        __syncthreads();
    }
    if (tid == 0) partials[blockIdx.x] = red[0];
}

__global__ __launch_bounds__(512) void scanB_kernel(int* __restrict__ partials, int B)
{
    __shared__ int s[512];
    const int tid = threadIdx.x;
    int v = (tid < B) ? partials[tid] : 0;
    s[tid] = v;
    __syncthreads();
    for (int d = 1; d < 512; d <<= 1) {
        int t = (tid >= d) ? s[tid - d] : 0;
        __syncthreads();
        s[tid] += t;
        __syncthreads();
    }
    if (tid < B) partials[tid] = s[tid] - v;  // inclusive -> exclusive
}

__global__ __launch_bounds__(256) void scanC_kernel(
    int* __restrict__ a, const int* __restrict__ partials, int T)
{
    __shared__ int s[256];
    const int tid = threadIdx.x;
    const int idx0 = blockIdx.x * 1024 + tid * 4;  // thread owns 4 contiguous
    int e0 = 0, e1 = 0, e2 = 0, e3 = 0;
    if (idx0     < T) e0 = a[idx0];
    if (idx0 + 1 < T) e1 = a[idx0 + 1];
    if (idx0 + 2 < T) e2 = a[idx0 + 2];
    if (idx0 + 3 < T) e3 = a[idx0 + 3];
    int ls = e0 + e1 + e2 + e3;
    s[tid] = ls;
    __syncthreads();
    for (int d = 1; d < 256; d <<= 1) {
        int t = (tid >= d) ? s[tid - d] : 0;
        __syncthreads();
        s[tid] += t;
        __syncthreads();
    }
    int ex = s[tid] - ls + partials[blockIdx.x];
    if (idx0     < T) a[idx0]     = ex;
    if (idx0 + 1 < T) a[idx0 + 1] = ex + e0;
    if (idx0 + 2 < T) a[idx0 + 2] = ex + e0 + e1;
    if (idx0 + 3 < T) a[idx0 + 3] = ex + e0 + e1 + e2;
}

// ---------------- P3: bucket-major scatter of packed (src|dstLow) ----------
__global__ __launch_bounds__(256) void p3_scatter_kernel(
    const int* __restrict__ src, const int* __restrict__ dst,
    const int* __restrict__ counts, unsigned* __restrict__ pairs,
    int E, int EB, int NB)
{
    __shared__ int cur[MAXNB];
    const int tid = threadIdx.x;
    for (int b = tid; b < NB; b += 256)
        cur[b] = counts[(size_t)b * EB + blockIdx.x];  // scanned base for (b, blk)
    __syncthreads();
    const int base = blockIdx.x * CHUNK;
#pragma unroll
    for (int k = 0; k < CHUNK / 256; ++k) {
        int e = base + k * 256 + tid;
        if (e < E) {
            int d = dst[e];
            int p = atomicAdd(&cur[d >> 8], 1);   // LDS atomic
            pairs[p] = (unsigned)src[e] | ((unsigned)(d & (BKT - 1)) << 17);
        }
    }
}

// ---------------- P4: in-bucket refine -> off + final srcs -----------------
__global__ __launch_bounds__(256) void p4_refine_kernel(
    const unsigned* __restrict__ pairs, const int* __restrict__ counts,
    int* __restrict__ off, int* __restrict__ srcs,
    int N, int E, int EB, int NB)
{
    __shared__ int cnt[BKT];
    __shared__ int s[BKT];
    __shared__ int pref[BKT];
    const int tid = threadIdx.x;
    const int b = blockIdx.x;
    const int start = counts[(size_t)b * EB];
    const int end = (b == NB - 1) ? E : counts[(size_t)(b + 1) * EB];

    cnt[tid] = 0;
    __syncthreads();
    for (int e = start + tid; e < end; e += 256)
        atomicAdd(&cnt[pairs[e] >> 17], 1);
    __syncthreads();

    int v = cnt[tid];
    s[tid] = v;
    __syncthreads();
    for (int d = 1; d < 256; d <<= 1) {
        int t = (tid >= d) ? s[tid - d] : 0;
        __syncthreads();
        s[tid] += t;
        __syncthreads();
    }
    int ex = s[tid] - v;
    pref[tid] = ex;
    int dg = b * BKT + tid;
    if (dg <= N) off[dg] = start + ex;   // dg==N (last bucket) -> off[N]=E
    __syncthreads();

    for (int e = start + tid; e < end; e += 256) {
        unsigned pr = pairs[e];
        int slot = start + atomicAdd(&pref[pr >> 17], 1);  // LDS atomic
        srcs[slot] = (int)(pr & 0x1FFFFu);
    }
}

// ---------------- K3: gather, 4-edge unroll, loads-first -------------------
__global__ __launch_bounds__(256) void gather_kernel(
    const int* __restrict__ off, const int* __restrict__ srcs,
    const float* __restrict__ packed, const float* __restrict__ er,
    const float* __restrict__ lin, float* __restrict__ out, int N)
{
    const int tid = threadIdx.x;
    const int nl = tid >> 2;
    const int cg = tid & 3;
    const int n = blockIdx.x * 64 + nl;
    if (n >= N) return;
    const int cbase = cg * 12;
    const int hA = cbase >> 4;
    const int hB = (cbase + 11) >> 4;
    const int jb0 = 16 - (cbase & 15);
    const int jb = jb0 > 12 ? 12 : jb0;          // j < jb -> head hA, else hB
    const bool twoHeads = (hB != hA);

    const float ernA = er[(size_t)n * H + hA];
    const float ernB = er[(size_t)n * H + hB];

    float acc[12];
#pragma unroll
    for (int j = 0; j < 12; ++j) acc[j] = 0.f;
    float denA = 0.f, denB = 0.f;

    const int start = off[n];
    const int end = off[n + 1];
    int e = start;

    // compute step shared by both paths (all indices compile-time constant)
#define COMPUTE(EV, U0, U1, U2, U3, U4, U5)                                    \
    {                                                                          \
        float elA = hA == 0 ? (EV).x : (hA == 1 ? (EV).y : (EV).z);            \
        float tA = elA + ernA;                                                 \
        tA = tA > 0.f ? tA : NEG_SLOPE * tA;                                   \
        float wA = __expf(tA);                                                 \
        denA += wA;                                                            \
        float wB = wA;                                                         \
        if (twoHeads) {                                                        \
            float elB = hB == 1 ? (EV).y : (EV).z;                             \
            float tB = elB + ernB;                                             \
            tB = tB > 0.f ? tB : NEG_SLOPE * tB;                               \
            wB = __expf(tB);                                                   \
            denB += wB;                                                        \
        }                                                                      \
        unsigned uu[6] = {U0, U1, U2, U3, U4, U5};                             \
        _Pragma("unroll")                                                      \
        for (int i = 0; i < 6; ++i) {                                          \
            float wlo = (2 * i < jb) ? wA : wB;                                \
            float whi = (2 * i + 1 < jb) ? wA : wB;                            \
            acc[2 * i]     += wlo * bflo(uu[i]);                               \
            acc[2 * i + 1] += whi * bfhi(uu[i]);                               \
        }                                                                      \
    }

    for (; e + 4 <= end; e += 4) {
        int s0 = srcs[e], s1 = srcs[e + 1], s2 = srcs[e + 2], s3 = srcs[e + 3];
        const float* r0 = packed + (size_t)s0 * RS;
        const float* r1 = packed + (size_t)s1 * RS;
        const float* r2 = packed + (size_t)s2 * RS;
        const float* r3 = packed + (size_t)s3 * RS;
        // issue ALL loads first (16 independent VMEM ops)
        float4 ev0 = *reinterpret_cast<const float4*>(r0 + 24);
        float4 ev1 = *reinterpret_cast<const float4*>(r1 + 24);
        float4 ev2 = *reinterpret_cast<const float4*>(r2 + 24);
        float4 ev3 = *reinterpret_cast<const float4*>(r3 + 24);
        const uint2* f0 = reinterpret_cast<const uint2*>(r0 + cg * 6);
        const uint2* f1 = reinterpret_cast<const uint2*>(r1 + cg * 6);
        const uint2* f2 = reinterpret_cast<const uint2*>(r2 + cg * 6);
        const uint2* f3 = reinterpret_cast<const uint2*>(r3 + cg * 6);
        uint2 a0 = f0[0], b0 = f0[1], c0 = f0[2];
        uint2 a1 = f1[0], b1 = f1[1], c1 = f1[2];
        uint2 a2 = f2[0], b2 = f2[1], c2 = f2[2];
        uint2 a3 = f3[0], b3 = f3[1], c3 = f3[2];
        COMPUTE(ev0, a0.x, a0.y, b0.x, b0.y, c0.x, c0.y);
        COMPUTE(ev1, a1.x, a1.y, b1.x, b1.y, c1.x, c1.y);
        COMPUTE(ev2, a2.x, a2.y, b2.x, b2.y, c2.x, c2.y);
        COMPUTE(ev3, a3.x, a3.y, b3.x, b3.y, c3.x, c3.y);
    }
    for (; e < end; ++e) {
        int s0 = srcs[e];
        const float* r0 = packed + (size_t)s0 * RS;
        float4 ev0 = *reinterpret_cast<const float4*>(r0 + 24);
        const uint2* f0 = reinterpret_cast<const uint2*>(r0 + cg * 6);
        uint2 a0 = f0[0], b0 = f0[1], c0 = f0[2];
        COMPUTE(ev0, a0.x, a0.y, b0.x, b0.y, c0.x, c0.y);
    }
#undef COMPUTE

    const float l = lin[n];
    const float om = 1.f - l;
    float invA = denA > 0.f ? 1.f / denA : 0.f;   // deg-0 node -> msg = 0
    float invB = twoHeads ? (denB > 0.f ? 1.f / denB : 0.f) : invA;

    const float* myrow = packed + (size_t)n * RS;
    const uint2* mp = reinterpret_cast<const uint2*>(myrow + cg * 6);
    uint2 m0 = mp[0], m1 = mp[1], m2 = mp[2];
    unsigned mu[6] = {m0.x, m0.y, m1.x, m1.y, m2.x, m2.y};

    float o[12];
#pragma unroll
    for (int i = 0; i < 6; ++i) {
        float ilo = (2 * i < jb) ? invA : invB;
        float ihi = (2 * i + 1 < jb) ? invA : invB;
        o[2 * i]     = om * (acc[2 * i] * ilo) + l * bflo(mu[i]);
        o[2 * i + 1] = om * (acc[2 * i + 1] * ihi) + l * bfhi(mu[i]);
    }
#pragma unroll
    for (int j = 0; j < 12; j += 4) {
        *reinterpret_cast<float4*>(&out[(size_t)n * C + cbase + j]) =
            make_float4(o[j], o[j + 1], o[j + 2], o[j + 3]);
    }
}

extern "C" void kernel_launch(void* const* d_in, const int* in_sizes, int n_in,
                              void* d_out, int out_size, void* d_ws, size_t ws_size,
                              hipStream_t stream)
{
    const float* x      = (const float*)d_in[0];
    const float* W      = (const float*)d_in[1];
    const float* attn_l = (const float*)d_in[2];
    const float* attn_r = (const float*)d_in[3];
    const float* lin    = (const float*)d_in[4];
    const int*   src    = (const int*)d_in[5];
    const int*   dst    = (const int*)d_in[6];
    const int N = in_sizes[4];
    const int E = in_sizes[5];
    float* out = (float*)d_out;

    const int NB = (N + BKT - 1) / BKT;        // 391 coarse buckets
    const int EB = (E + CHUNK - 1) / CHUNK;    // 391 edge blocks
    const int T  = NB * EB;                    // 152,881 counts
    const int SBlk = (T + 1023) / 1024;        // 150 scan blocks (<= 512)

    // workspace layout (packed first -> 128B row alignment)
    float*    packed   = (float*)d_ws;                   // N*RS floats
    float*    er       = packed + (size_t)N * RS;        // N*H floats
    unsigned* pairs    = (unsigned*)(er + (size_t)N * H);// E uints
    int*      counts   = (int*)(pairs + E);              // T ints
    int*      partials = counts + T;                     // 1024
    int*      off      = partials + 1024;                // N+1
    int*      srcs     = off + (N + 1);                  // E
    // every word read is written by an earlier kernel (no memset needed)

    feat_kernel<<<(N + 63) / 64, 256, 0, stream>>>(
        x, W, attn_l, attn_r, packed, er, N);
    p1_count_kernel<<<EB, 256, 0, stream>>>(dst, counts, E, EB, NB);
    scanA_kernel<<<SBlk, 256, 0, stream>>>(counts, partials, T);
    scanB_kernel<<<1, 512, 0, stream>>>(partials, SBlk);
    scanC_kernel<<<SBlk, 256, 0, stream>>>(counts, partials, T);
    p3_scatter_kernel<<<EB, 256, 0, stream>>>(src, dst, counts, pairs, E, EB, NB);
    p4_refine_kernel<<<NB, 256, 0, stream>>>(pairs, counts, off, srcs, N, E, EB, NB);
    gather_kernel<<<(N + 63) / 64, 256, 0, stream>>>(
        off, srcs, packed, er, lin, out, N);
}